// Round 1
// baseline (3404.222 us; speedup 1.0000x reference)
//
#include <hip/hip_runtime.h>
#include <math.h>

#define B_ 4
#define S_ 2048
#define E_ 512
#define H_ 8
#define Dh_ 64
#define BS_ (B_*S_)
#define MAXN 0.996f   // (1 - 4e-3)/sqrt(c), c=1

__device__ __forceinline__ float wave_reduce_sum(float v) {
  #pragma unroll
  for (int off = 32; off > 0; off >>= 1) v += __shfl_xor(v, off, 64);
  return v;
}

// ---- P1: per-row stats of a [BS_, E_] matrix: xn = max(||row||,1e-15), art = artanh(clip(xn))
__global__ __launch_bounds__(256) void row_stats_kernel(const float* __restrict__ X,
                                                        float* __restrict__ xn_out,
                                                        float* __restrict__ art_out) {
  int row = blockIdx.x * 4 + (threadIdx.x >> 6);
  int lane = threadIdx.x & 63;
  const float4* xr = (const float4*)(X + (size_t)row * E_) + lane * 2;
  float4 a = xr[0], b = xr[1];
  float s = a.x*a.x + a.y*a.y + a.z*a.z + a.w*a.w
          + b.x*b.x + b.y*b.y + b.z*b.z + b.w*b.w;
  s = wave_reduce_sum(s);
  if (lane == 0) {
    float xn = fmaxf(sqrtf(s), 1e-15f);
    float aa = fminf(xn, 1.f - 1e-7f);          // artanh clip
    xn_out[row] = xn;
    art_out[row] = 0.5f * (log1pf(aa) - log1pf(-aa));
  }
}

// ---- P2: per-(b,h,s) head norms of Q and K, clipped to 1-1e-5
__global__ __launch_bounds__(256) void head_norm_kernel(const float* __restrict__ Q,
                                                        const float* __restrict__ K,
                                                        float* __restrict__ qn,
                                                        float* __restrict__ kn) {
  int row = blockIdx.x * 4 + (threadIdx.x >> 6);   // global row in [0, BS_)
  int lane = threadIdx.x & 63;
  const float* src = blockIdx.y ? K : Q;
  float* dst = blockIdx.y ? kn : qn;
  const float4* xr = (const float4*)(src + (size_t)row * E_) + lane * 2;
  float4 a = xr[0], b = xr[1];
  float s = a.x*a.x + a.y*a.y + a.z*a.z + a.w*a.w
          + b.x*b.x + b.y*b.y + b.z*b.z + b.w*b.w;
  // lane covers cols [lane*8, lane*8+8) -> head = lane>>3; reduce within 8-lane group
  s += __shfl_xor(s, 1, 64); s += __shfl_xor(s, 2, 64); s += __shfl_xor(s, 4, 64);
  if ((lane & 7) == 0) {
    int h = lane >> 3;
    int b_ = row >> 11, sidx = row & (S_ - 1);
    dst[((size_t)(b_*H_ + h))*S_ + sidx] = fminf(s, 1.f - 1e-5f);
  }
}

// ---- A: out = project(mobius_add(project(mobius_matvec(W, X)), bvec)) per row.
// One block = 16 rows x all 512 cols. X read via wave-uniform (scalar) loads,
// W streamed per-lane in full-cacheline register chunks.
__global__ __launch_bounds__(256, 2) void hyp_linear_kernel(const float* __restrict__ X,
    const float* __restrict__ W, const float* __restrict__ bvec,
    const float* __restrict__ xn_arr, const float* __restrict__ art_arr,
    float* __restrict__ out) {
  int tid = threadIdx.x;
  int wid = tid >> 6, lane = tid & 63;
  int row0 = blockIdx.x * 16;
  float acc0[16], acc1[16];
  #pragma unroll
  for (int r = 0; r < 16; ++r) { acc0[r] = 0.f; acc1[r] = 0.f; }
  const float* w0 = W + (size_t)tid * E_;          // lane's col jt = tid
  const float* w1 = W + (size_t)(tid + 256) * E_;  // and jt+256
  const float* x0 = X + (size_t)row0 * E_;
  #pragma unroll 1
  for (int c = 0; c < 16; ++c) {                   // 16 chunks of 32 k
    const int k0 = c * 32;
    float4 wa[8], wb[8];
    #pragma unroll
    for (int i = 0; i < 8; ++i) {                  // 128B per row: full line consumed
      wa[i] = *(const float4*)(w0 + k0 + 4*i);
      wb[i] = *(const float4*)(w1 + k0 + 4*i);
    }
    #pragma unroll
    for (int r = 0; r < 16; ++r) {
      const float* xr = x0 + (size_t)r * E_ + k0;  // uniform address -> s_load
      #pragma unroll
      for (int i = 0; i < 8; ++i) {
        float xv0 = xr[4*i+0], xv1 = xr[4*i+1], xv2 = xr[4*i+2], xv3 = xr[4*i+3];
        acc0[r] = fmaf(xv0, wa[i].x, acc0[r]);
        acc0[r] = fmaf(xv1, wa[i].y, acc0[r]);
        acc0[r] = fmaf(xv2, wa[i].z, acc0[r]);
        acc0[r] = fmaf(xv3, wa[i].w, acc0[r]);
        acc1[r] = fmaf(xv0, wb[i].x, acc1[r]);
        acc1[r] = fmaf(xv1, wb[i].y, acc1[r]);
        acc1[r] = fmaf(xv2, wb[i].z, acc1[r]);
        acc1[r] = fmaf(xv3, wb[i].w, acc1[r]);
      }
    }
  }
  // ---- epilogue: per-row scalars via reductions, then affine write
  __shared__ float redM[4][16], redB[4][16], redS[4];
  float bl0 = bvec[tid], bl1 = bvec[tid + 256];
  float pb2 = wave_reduce_sum(bl0*bl0 + bl1*bl1);
  if (lane == 0) redS[wid] = pb2;
  #pragma unroll
  for (int r = 0; r < 16; ++r) {
    float pm = wave_reduce_sum(acc0[r]*acc0[r] + acc1[r]*acc1[r]);
    float pb = wave_reduce_sum(acc0[r]*bl0 + acc1[r]*bl1);
    if (lane == 0) { redM[wid][r] = pm; redB[wid][r] = pb; }
  }
  __syncthreads();
  float b2 = redS[0] + redS[1] + redS[2] + redS[3];
  #pragma unroll
  for (int r = 0; r < 16; ++r) {
    float m2 = redM[0][r]+redM[1][r]+redM[2][r]+redM[3][r];   // ||mx||^2
    float mb = redB[0][r]+redB[1][r]+redB[2][r]+redB[3][r];   // mx . b
    float xn = xn_arr[row0 + r], art = art_arr[row0 + r];
    float mn = fmaxf(sqrtf(m2), 1e-15f);
    float t = tanhf(mn / xn * art);
    float alpha, rn;
    if (m2 > 0.f) { alpha = t / mn; rn = t; } else { alpha = 0.f; rn = 0.f; }
    if (rn > MAXN) { alpha *= MAXN / rn; rn = MAXN; }          // project(res)
    float x2r = rn * rn;
    float xy = alpha * mb;                                     // res . b
    float A  = 1.f + 2.f*xy + b2;
    float Bc = 1.f - x2r;
    float den = fmaxf(1.f + 2.f*xy + x2r*b2, 1e-15f);
    float n2 = (A*A*x2r + 2.f*A*Bc*xy + Bc*Bc*b2) / (den*den); // ||num/den||^2
    float nn = fmaxf(sqrtf(n2), 1e-15f);
    float sc = (nn > MAXN) ? (MAXN / nn) : 1.f;                // project(add)
    float G  = sc * A * alpha / den;
    float Hb = sc * Bc / den;
    size_t o = (size_t)(row0 + r) * E_;
    out[o + tid]       = G*acc0[r] + Hb*bl0;
    out[o + tid + 256] = G*acc1[r] + Hb*bl1;
  }
}

// ---- Attention: thread-per-q-row flash with hyperbolic scores.
// K/V rows are wave-uniform -> scalar loads; no LDS, no syncthreads.
__global__ __launch_bounds__(64, 1) void attn_kernel(const float* __restrict__ Q,
    const float* __restrict__ K, const float* __restrict__ V,
    const float* __restrict__ qn_arr, const float* __restrict__ kn_arr,
    float* __restrict__ Out) {
  int lane = threadIdx.x;
  int qblk = blockIdx.x;
  int bh = blockIdx.y;
  int b = bh >> 3, h = bh & 7;
  int qrow = qblk * 64 + lane;
  const float* qp = Q + ((size_t)(b*S_ + qrow))*E_ + h*Dh_;
  float4 q4[16];
  #pragma unroll
  for (int i = 0; i < 16; ++i) q4[i] = *(const float4*)(qp + 4*i);
  float qn = qn_arr[(size_t)bh*S_ + qrow];
  float qd = 1.f - qn;
  float4 o4[16];
  #pragma unroll
  for (int i = 0; i < 16; ++i) o4[i] = make_float4(0.f,0.f,0.f,0.f);
  float m = -3e38f, l = 0.f;
  const float* Kb = K + ((size_t)b*S_)*E_ + h*Dh_;
  const float* Vb = V + ((size_t)b*S_)*E_ + h*Dh_;
  const float* knb = kn_arr + (size_t)bh*S_;
  #pragma unroll 1
  for (int kt = 0; kt < S_; kt += 8) {
    float sc[8];
    #pragma unroll
    for (int j = 0; j < 8; ++j) {
      const float* kr = Kb + (size_t)(kt + j)*E_;   // uniform -> s_load
      float p0=0.f, p1=0.f, p2=0.f, p3=0.f;
      #pragma unroll
      for (int i = 0; i < 16; ++i) {
        p0 = fmaf(q4[i].x, kr[4*i+0], p0);
        p1 = fmaf(q4[i].y, kr[4*i+1], p1);
        p2 = fmaf(q4[i].z, kr[4*i+2], p2);
        p3 = fmaf(q4[i].w, kr[4*i+3], p3);
      }
      float qk = (p0+p1)+(p2+p3);
      float knv = knb[kt + j];
      float den = qd*(1.f - knv) + 1e-5f;
      float delta = 2.f*(qk - qn*knv)/den;
      sc[j] = -0.125f * sqrtf(fmaxf(delta, 1e-5f));  // -dist/sqrt(Dh)
    }
    float tm = fmaxf(fmaxf(fmaxf(sc[0],sc[1]),fmaxf(sc[2],sc[3])),
                     fmaxf(fmaxf(sc[4],sc[5]),fmaxf(sc[6],sc[7])));
    if (tm > m) {                                    // rescale only when max grows
      float corr = __expf(m - tm);
      l *= corr;
      #pragma unroll
      for (int i = 0; i < 16; ++i) {
        o4[i].x *= corr; o4[i].y *= corr; o4[i].z *= corr; o4[i].w *= corr;
      }
      m = tm;
    }
    #pragma unroll
    for (int j = 0; j < 8; ++j) {
      float p = __expf(sc[j] - m);
      l += p;
      const float* vr = Vb + (size_t)(kt + j)*E_;   // uniform -> s_load
      #pragma unroll
      for (int i = 0; i < 16; ++i) {
        o4[i].x = fmaf(p, vr[4*i+0], o4[i].x);
        o4[i].y = fmaf(p, vr[4*i+1], o4[i].y);
        o4[i].z = fmaf(p, vr[4*i+2], o4[i].z);
        o4[i].w = fmaf(p, vr[4*i+3], o4[i].w);
      }
    }
  }
  float inv = 1.f / l;
  float* op = Out + ((size_t)(b*S_ + qrow))*E_ + h*Dh_;
  #pragma unroll
  for (int i = 0; i < 16; ++i) {
    float4 r = o4[i];
    r.x *= inv; r.y *= inv; r.z *= inv; r.w *= inv;
    *(float4*)(op + 4*i) = r;
  }
}

extern "C" void kernel_launch(void* const* d_in, const int* in_sizes, int n_in,
                              void* d_out, int out_size, void* d_ws, size_t ws_size,
                              hipStream_t stream) {
  const float* x  = (const float*)d_in[0];
  const float* Wq = (const float*)d_in[1];
  const float* bq = (const float*)d_in[2];
  const float* Wk = (const float*)d_in[3];
  const float* bk = (const float*)d_in[4];
  const float* Wv = (const float*)d_in[5];
  const float* bv = (const float*)d_in[6];
  const float* Wo = (const float*)d_in[7];
  const float* bo = (const float*)d_in[8];
  float* out = (float*)d_out;

  float* ws   = (float*)d_ws;
  float* q    = ws;                         // BS_*E_
  float* k    = q  + (size_t)BS_*E_;        // BS_*E_
  float* v    = k  + (size_t)BS_*E_;        // BS_*E_
  float* xn   = v  + (size_t)BS_*E_;        // BS_
  float* art  = xn  + BS_;                  // BS_
  float* xn2  = art + BS_;                  // BS_
  float* art2 = xn2 + BS_;                  // BS_
  float* qn   = art2 + BS_;                 // B_*H_*S_
  float* kn   = qn + (size_t)B_*H_*S_;      // B_*H_*S_
  // total ~48.6 MiB of ws

  row_stats_kernel<<<dim3(BS_/4), dim3(256), 0, stream>>>(x, xn, art);
  hyp_linear_kernel<<<dim3(BS_/16), dim3(256), 0, stream>>>(x, Wq, bq, xn, art, q);
  hyp_linear_kernel<<<dim3(BS_/16), dim3(256), 0, stream>>>(x, Wk, bk, xn, art, k);
  hyp_linear_kernel<<<dim3(BS_/16), dim3(256), 0, stream>>>(x, Wv, bv, xn, art, v);
  head_norm_kernel<<<dim3(BS_/4, 2), dim3(256), 0, stream>>>(q, k, qn, kn);
  attn_kernel<<<dim3(S_/64, B_*H_), dim3(64), 0, stream>>>(q, k, v, qn, kn, out);
  row_stats_kernel<<<dim3(BS_/4), dim3(256), 0, stream>>>(out, xn2, art2);
  // in-place final linear is safe: each block reads only its own 16 rows, writes them last
  hyp_linear_kernel<<<dim3(BS_/16), dim3(256), 0, stream>>>(out, Wo, bo, xn2, art2, out);
}

// Round 2
// 2694.271 us; speedup vs baseline: 1.2635x; 1.2635x over previous
//
#include <hip/hip_runtime.h>
#include <math.h>

#define B_ 4
#define S_ 2048
#define E_ 512
#define H_ 8
#define Dh_ 64
#define BS_ (B_*S_)
#define MAXN 0.996f   // (1 - 4e-3)/sqrt(c), c=1

__device__ __forceinline__ float wave_reduce_sum(float v) {
  #pragma unroll
  for (int off = 32; off > 0; off >>= 1) v += __shfl_xor(v, off, 64);
  return v;
}

// ---- P1: per-row stats of a [BS_, E_] matrix: xn = max(||row||,1e-15), art = artanh(clip(xn))
__global__ __launch_bounds__(256) void row_stats_kernel(const float* __restrict__ X,
                                                        float* __restrict__ xn_out,
                                                        float* __restrict__ art_out) {
  int row = blockIdx.x * 4 + (threadIdx.x >> 6);
  int lane = threadIdx.x & 63;
  const float4* xr = (const float4*)(X + (size_t)row * E_) + lane * 2;
  float4 a = xr[0], b = xr[1];
  float s = a.x*a.x + a.y*a.y + a.z*a.z + a.w*a.w
          + b.x*b.x + b.y*b.y + b.z*b.z + b.w*b.w;
  s = wave_reduce_sum(s);
  if (lane == 0) {
    float xn = fmaxf(sqrtf(s), 1e-15f);
    float aa = fminf(xn, 1.f - 1e-7f);          // artanh clip
    xn_out[row] = xn;
    art_out[row] = 0.5f * (log1pf(aa) - log1pf(-aa));
  }
}

// ---- P2: per-(b,h,s) head norms of Q and K, clipped to 1-1e-5
__global__ __launch_bounds__(256) void head_norm_kernel(const float* __restrict__ Q,
                                                        const float* __restrict__ K,
                                                        float* __restrict__ qn,
                                                        float* __restrict__ kn) {
  int row = blockIdx.x * 4 + (threadIdx.x >> 6);   // global row in [0, BS_)
  int lane = threadIdx.x & 63;
  const float* src = blockIdx.y ? K : Q;
  float* dst = blockIdx.y ? kn : qn;
  const float4* xr = (const float4*)(src + (size_t)row * E_) + lane * 2;
  float4 a = xr[0], b = xr[1];
  float s = a.x*a.x + a.y*a.y + a.z*a.z + a.w*a.w
          + b.x*b.x + b.y*b.y + b.z*b.z + b.w*b.w;
  s += __shfl_xor(s, 1, 64); s += __shfl_xor(s, 2, 64); s += __shfl_xor(s, 4, 64);
  if ((lane & 7) == 0) {
    int h = lane >> 3;
    int b_ = row >> 11, sidx = row & (S_ - 1);
    dst[((size_t)(b_*H_ + h))*S_ + sidx] = fminf(s, 1.f - 1e-5f);
  }
}

// ---- A: out = project(mobius_add(project(mobius_matvec(W, X)), bvec)) per row.
// One block = 16 rows x all 512 cols. X read via VMEM broadcast loads (uniform
// address made opaque-divergent so the compiler uses the deep vmcnt queue),
// W streamed per-lane in full-cacheline register chunks.
__global__ __launch_bounds__(256, 2) void hyp_linear_kernel(const float* __restrict__ X,
    const float* __restrict__ W, const float* __restrict__ bvec,
    const float* __restrict__ xn_arr, const float* __restrict__ art_arr,
    float* __restrict__ out) {
  int tid = threadIdx.x;
  int wid = tid >> 6, lane = tid & 63;
  int row0 = blockIdx.x * 16;
  float acc0[16], acc1[16];
  #pragma unroll
  for (int r = 0; r < 16; ++r) { acc0[r] = 0.f; acc1[r] = 0.f; }
  const float* w0 = W + (size_t)tid * E_;          // lane's col jt = tid
  const float* w1 = W + (size_t)(tid + 256) * E_;  // and jt+256
  const float* x0 = X + (size_t)row0 * E_;
  #pragma unroll 1
  for (int c = 0; c < 16; ++c) {                   // 16 chunks of 32 k
    const int k0 = c * 32;
    int cb = __shfl(k0, 0);                        // opaque-divergent chunk base -> VMEM
    float4 wa[8], wb[8];
    #pragma unroll
    for (int i = 0; i < 8; ++i) {                  // 128B per row: full line consumed
      wa[i] = *(const float4*)(w0 + k0 + 4*i);
      wb[i] = *(const float4*)(w1 + k0 + 4*i);
    }
    #pragma unroll
    for (int r = 0; r < 16; ++r) {
      const float4* xr = (const float4*)(x0 + (size_t)r * E_ + cb);
      float4 xv[8];
      #pragma unroll
      for (int i = 0; i < 8; ++i) xv[i] = xr[i];
      #pragma unroll
      for (int i = 0; i < 8; ++i) {
        acc0[r] = fmaf(xv[i].x, wa[i].x, acc0[r]);
        acc0[r] = fmaf(xv[i].y, wa[i].y, acc0[r]);
        acc0[r] = fmaf(xv[i].z, wa[i].z, acc0[r]);
        acc0[r] = fmaf(xv[i].w, wa[i].w, acc0[r]);
        acc1[r] = fmaf(xv[i].x, wb[i].x, acc1[r]);
        acc1[r] = fmaf(xv[i].y, wb[i].y, acc1[r]);
        acc1[r] = fmaf(xv[i].z, wb[i].z, acc1[r]);
        acc1[r] = fmaf(xv[i].w, wb[i].w, acc1[r]);
      }
    }
  }
  // ---- epilogue: per-row scalars via reductions, then affine write
  __shared__ float redM[4][16], redB[4][16], redS[4];
  float bl0 = bvec[tid], bl1 = bvec[tid + 256];
  float pb2 = wave_reduce_sum(bl0*bl0 + bl1*bl1);
  if (lane == 0) redS[wid] = pb2;
  #pragma unroll
  for (int r = 0; r < 16; ++r) {
    float pm = wave_reduce_sum(acc0[r]*acc0[r] + acc1[r]*acc1[r]);
    float pb = wave_reduce_sum(acc0[r]*bl0 + acc1[r]*bl1);
    if (lane == 0) { redM[wid][r] = pm; redB[wid][r] = pb; }
  }
  __syncthreads();
  float b2 = redS[0] + redS[1] + redS[2] + redS[3];
  #pragma unroll
  for (int r = 0; r < 16; ++r) {
    float m2 = redM[0][r]+redM[1][r]+redM[2][r]+redM[3][r];   // ||mx||^2
    float mb = redB[0][r]+redB[1][r]+redB[2][r]+redB[3][r];   // mx . b
    float xn = xn_arr[row0 + r], art = art_arr[row0 + r];
    float mn = fmaxf(sqrtf(m2), 1e-15f);
    float t = tanhf(mn / xn * art);
    float alpha, rn;
    if (m2 > 0.f) { alpha = t / mn; rn = t; } else { alpha = 0.f; rn = 0.f; }
    if (rn > MAXN) { alpha *= MAXN / rn; rn = MAXN; }          // project(res)
    float x2r = rn * rn;
    float xy = alpha * mb;                                     // res . b
    float A  = 1.f + 2.f*xy + b2;
    float Bc = 1.f - x2r;
    float den = fmaxf(1.f + 2.f*xy + x2r*b2, 1e-15f);
    float n2 = (A*A*x2r + 2.f*A*Bc*xy + Bc*Bc*b2) / (den*den); // ||num/den||^2
    float nn = fmaxf(sqrtf(n2), 1e-15f);
    float sc = (nn > MAXN) ? (MAXN / nn) : 1.f;                // project(add)
    float G  = sc * A * alpha / den;
    float Hb = sc * Bc / den;
    size_t o = (size_t)(row0 + r) * E_;
    out[o + tid]       = G*acc0[r] + Hb*bl0;
    out[o + tid + 256] = G*acc1[r] + Hb*bl1;
  }
}

// ---- Attention v2: 4-wave blocks; each wave = same 64 q-rows, 1/4 of K range.
// Scores are provably in [-79.1, 0] (norms clipped at 1-1e-5), so softmax uses
// fixed m=0: no online max, partials combine by plain sums in LDS.
// K/V/kn rows read via VMEM broadcast loads (opaque-divergent base).
__global__ __launch_bounds__(256, 2) void attn_kernel(const float* __restrict__ Q,
    const float* __restrict__ K, const float* __restrict__ V,
    const float* __restrict__ qn_arr, const float* __restrict__ kn_arr,
    float* __restrict__ Out) {
  __shared__ float Obuf[4][64][68];   // padded stride 68 to spread banks
  __shared__ float Lbuf[4][64];
  int tid = threadIdx.x;
  int w = tid >> 6, lane = tid & 63;
  // XCD swizzle: same bh -> same XCD (assuming round-robin blockIdx%8 placement)
  int bid = blockIdx.x;               // 0..1023
  int xcd = bid & 7;
  int i2  = bid >> 3;                 // 0..127
  int bh  = xcd + 8 * (i2 & 3);       // 0..31
  int qblk = i2 >> 2;                 // 0..31
  int b = bh >> 3, h = bh & 7;
  int qrow = qblk * 64 + lane;
  const float* qp = Q + ((size_t)(b*S_ + qrow))*E_ + h*Dh_;
  float4 q4[16];
  #pragma unroll
  for (int i = 0; i < 16; ++i) q4[i] = *(const float4*)(qp + 4*i);
  float qn = qn_arr[(size_t)bh*S_ + qrow];
  float qd = 1.f - qn;
  float4 o4[16];
  #pragma unroll
  for (int i = 0; i < 16; ++i) o4[i] = make_float4(0.f,0.f,0.f,0.f);
  float l = 0.f;
  const float* Kb = K + ((size_t)b*S_)*E_ + h*Dh_;
  const float* Vb = V + ((size_t)b*S_)*E_ + h*Dh_;
  const float* knb = kn_arr + (size_t)bh*S_;
  int base = __shfl(w * 512, 0);      // opaque-divergent k-chunk base -> VMEM path
  #pragma unroll 1
  for (int j = 0; j < 512; ++j) {
    const float* kr = Kb + (size_t)(base + j) * E_;
    float knv = knb[base + j];        // VMEM b32 broadcast, pipelined with K row
    float4 ka[16];
    #pragma unroll
    for (int i = 0; i < 16; ++i) ka[i] = *(const float4*)(kr + 4*i);
    float p0=0.f, p1=0.f, p2=0.f, p3=0.f;
    #pragma unroll
    for (int i = 0; i < 16; ++i) {
      p0 = fmaf(q4[i].x, ka[i].x, p0);
      p1 = fmaf(q4[i].y, ka[i].y, p1);
      p2 = fmaf(q4[i].z, ka[i].z, p2);
      p3 = fmaf(q4[i].w, ka[i].w, p3);
    }
    float qk = (p0+p1)+(p2+p3);
    float den = qd*(1.f - knv) + 1e-5f;
    float delta = 2.f*(qk - qn*knv) * __frcp_rn(den);
    float sc = -0.125f * sqrtf(fmaxf(delta, 1e-5f));  // -dist/sqrt(Dh), always <= 0
    float p = __expf(sc);
    l += p;
    const float* vr = Vb + (size_t)(base + j) * E_;
    #pragma unroll
    for (int i = 0; i < 16; ++i) {
      float4 va = *(const float4*)(vr + 4*i);
      o4[i].x = fmaf(p, va.x, o4[i].x);
      o4[i].y = fmaf(p, va.y, o4[i].y);
      o4[i].z = fmaf(p, va.z, o4[i].z);
      o4[i].w = fmaf(p, va.w, o4[i].w);
    }
  }
  // write partials
  Lbuf[w][lane] = l;
  #pragma unroll
  for (int i = 0; i < 16; ++i)
    *(float4*)&Obuf[w][lane][4*i] = o4[i];
  __syncthreads();
  // combine: thread t -> row r = t>>2, quarter dg = t&3 (16 floats each)
  int r = tid >> 2, dg = tid & 3;
  float lt = Lbuf[0][r] + Lbuf[1][r] + Lbuf[2][r] + Lbuf[3][r];
  float inv = 1.f / lt;
  float* op = Out + ((size_t)(b*S_ + qblk*64 + r))*E_ + h*Dh_ + dg*16;
  #pragma unroll
  for (int i = 0; i < 4; ++i) {
    float4 s0 = *(const float4*)&Obuf[0][r][dg*16 + 4*i];
    float4 s1 = *(const float4*)&Obuf[1][r][dg*16 + 4*i];
    float4 s2 = *(const float4*)&Obuf[2][r][dg*16 + 4*i];
    float4 s3 = *(const float4*)&Obuf[3][r][dg*16 + 4*i];
    float4 rr;
    rr.x = (s0.x+s1.x+s2.x+s3.x)*inv;
    rr.y = (s0.y+s1.y+s2.y+s3.y)*inv;
    rr.z = (s0.z+s1.z+s2.z+s3.z)*inv;
    rr.w = (s0.w+s1.w+s2.w+s3.w)*inv;
    *(float4*)(op + 4*i) = rr;
  }
}

extern "C" void kernel_launch(void* const* d_in, const int* in_sizes, int n_in,
                              void* d_out, int out_size, void* d_ws, size_t ws_size,
                              hipStream_t stream) {
  const float* x  = (const float*)d_in[0];
  const float* Wq = (const float*)d_in[1];
  const float* bq = (const float*)d_in[2];
  const float* Wk = (const float*)d_in[3];
  const float* bk = (const float*)d_in[4];
  const float* Wv = (const float*)d_in[5];
  const float* bv = (const float*)d_in[6];
  const float* Wo = (const float*)d_in[7];
  const float* bo = (const float*)d_in[8];
  float* out = (float*)d_out;

  float* ws   = (float*)d_ws;
  float* q    = ws;                         // BS_*E_
  float* k    = q  + (size_t)BS_*E_;        // BS_*E_
  float* v    = k  + (size_t)BS_*E_;        // BS_*E_
  float* xn   = v  + (size_t)BS_*E_;        // BS_
  float* art  = xn  + BS_;                  // BS_
  float* xn2  = art + BS_;                  // BS_
  float* art2 = xn2 + BS_;                  // BS_
  float* qn   = art2 + BS_;                 // B_*H_*S_
  float* kn   = qn + (size_t)B_*H_*S_;      // B_*H_*S_
  // total ~48.6 MiB of ws

  row_stats_kernel<<<dim3(BS_/4), dim3(256), 0, stream>>>(x, xn, art);
  hyp_linear_kernel<<<dim3(BS_/16), dim3(256), 0, stream>>>(x, Wq, bq, xn, art, q);
  hyp_linear_kernel<<<dim3(BS_/16), dim3(256), 0, stream>>>(x, Wk, bk, xn, art, k);
  hyp_linear_kernel<<<dim3(BS_/16), dim3(256), 0, stream>>>(x, Wv, bv, xn, art, v);
  head_norm_kernel<<<dim3(BS_/4, 2), dim3(256), 0, stream>>>(q, k, qn, kn);
  attn_kernel<<<dim3(32*32), dim3(256), 0, stream>>>(q, k, v, qn, kn, out);
  row_stats_kernel<<<dim3(BS_/4), dim3(256), 0, stream>>>(out, xn2, art2);
  // in-place final linear is safe: each block reads only its own 16 rows, writes them last
  hyp_linear_kernel<<<dim3(BS_/16), dim3(256), 0, stream>>>(out, Wo, bo, xn2, art2, out);
}

// Round 3
// 1260.009 us; speedup vs baseline: 2.7017x; 2.1383x over previous
//
#include <hip/hip_runtime.h>
#include <math.h>

#define B_ 4
#define S_ 2048
#define E_ 512
#define H_ 8
#define Dh_ 64
#define BS_ (B_*S_)
#define MAXN 0.996f   // (1 - 4e-3)/sqrt(c), c=1

typedef __attribute__((ext_vector_type(8))) short short8;
typedef __attribute__((ext_vector_type(4))) float f32x4;

__device__ __forceinline__ float wave_reduce_sum(float v) {
  #pragma unroll
  for (int off = 32; off > 0; off >>= 1) v += __shfl_xor(v, off, 64);
  return v;
}

__device__ __forceinline__ unsigned f2bf(float x) {            // RNE f32->bf16 bits
  unsigned u = __float_as_uint(x);
  return (u + 0x7fffu + ((u >> 16) & 1u)) >> 16;
}
__device__ __forceinline__ float bf2f(unsigned b) {
  return __uint_as_float(b << 16);
}

// ---- P1: per-row stats: xn = max(||row||,1e-15), art = artanh(clip(xn))
__global__ __launch_bounds__(256) void row_stats_kernel(const float* __restrict__ X,
                                                        float* __restrict__ xn_out,
                                                        float* __restrict__ art_out) {
  int row = blockIdx.x * 4 + (threadIdx.x >> 6);
  int lane = threadIdx.x & 63;
  const float4* xr = (const float4*)(X + (size_t)row * E_) + lane * 2;
  float4 a = xr[0], b = xr[1];
  float s = a.x*a.x + a.y*a.y + a.z*a.z + a.w*a.w
          + b.x*b.x + b.y*b.y + b.z*b.z + b.w*b.w;
  s = wave_reduce_sum(s);
  if (lane == 0) {
    float xn = fmaxf(sqrtf(s), 1e-15f);
    float aa = fminf(xn, 1.f - 1e-7f);
    xn_out[row] = xn;
    art_out[row] = 0.5f * (log1pf(aa) - log1pf(-aa));
  }
}

// ---- P2: per-(b,h,s) head norms of Q and K, clipped to 1-1e-5
__global__ __launch_bounds__(256) void head_norm_kernel(const float* __restrict__ Q,
                                                        const float* __restrict__ K,
                                                        float* __restrict__ qn,
                                                        float* __restrict__ kn) {
  int row = blockIdx.x * 4 + (threadIdx.x >> 6);
  int lane = threadIdx.x & 63;
  const float* src = blockIdx.y ? K : Q;
  float* dst = blockIdx.y ? kn : qn;
  const float4* xr = (const float4*)(src + (size_t)row * E_) + lane * 2;
  float4 a = xr[0], b = xr[1];
  float s = a.x*a.x + a.y*a.y + a.z*a.z + a.w*a.w
          + b.x*b.x + b.y*b.y + b.z*b.z + b.w*b.w;
  s += __shfl_xor(s, 1, 64); s += __shfl_xor(s, 2, 64); s += __shfl_xor(s, 4, 64);
  if ((lane & 7) == 0) {
    int h = lane >> 3;
    int b_ = row >> 11, sidx = row & (S_ - 1);
    dst[((size_t)(b_*H_ + h))*S_ + sidx] = fminf(s, 1.f - 1e-5f);
  }
}

// ---- hyp_linear (unchanged from round 2)
__global__ __launch_bounds__(256, 2) void hyp_linear_kernel(const float* __restrict__ X,
    const float* __restrict__ W, const float* __restrict__ bvec,
    const float* __restrict__ xn_arr, const float* __restrict__ art_arr,
    float* __restrict__ out) {
  int tid = threadIdx.x;
  int wid = tid >> 6, lane = tid & 63;
  int row0 = blockIdx.x * 16;
  float acc0[16], acc1[16];
  #pragma unroll
  for (int r = 0; r < 16; ++r) { acc0[r] = 0.f; acc1[r] = 0.f; }
  const float* w0 = W + (size_t)tid * E_;
  const float* w1 = W + (size_t)(tid + 256) * E_;
  const float* x0 = X + (size_t)row0 * E_;
  #pragma unroll 1
  for (int c = 0; c < 16; ++c) {
    const int k0 = c * 32;
    int cb = __shfl(k0, 0);
    float4 wa[8], wb[8];
    #pragma unroll
    for (int i = 0; i < 8; ++i) {
      wa[i] = *(const float4*)(w0 + k0 + 4*i);
      wb[i] = *(const float4*)(w1 + k0 + 4*i);
    }
    #pragma unroll
    for (int r = 0; r < 16; ++r) {
      const float4* xr = (const float4*)(x0 + (size_t)r * E_ + cb);
      float4 xv[8];
      #pragma unroll
      for (int i = 0; i < 8; ++i) xv[i] = xr[i];
      #pragma unroll
      for (int i = 0; i < 8; ++i) {
        acc0[r] = fmaf(xv[i].x, wa[i].x, acc0[r]);
        acc0[r] = fmaf(xv[i].y, wa[i].y, acc0[r]);
        acc0[r] = fmaf(xv[i].z, wa[i].z, acc0[r]);
        acc0[r] = fmaf(xv[i].w, wa[i].w, acc0[r]);
        acc1[r] = fmaf(xv[i].x, wb[i].x, acc1[r]);
        acc1[r] = fmaf(xv[i].y, wb[i].y, acc1[r]);
        acc1[r] = fmaf(xv[i].z, wb[i].z, acc1[r]);
        acc1[r] = fmaf(xv[i].w, wb[i].w, acc1[r]);
      }
    }
  }
  __shared__ float redM[4][16], redB[4][16], redS[4];
  float bl0 = bvec[tid], bl1 = bvec[tid + 256];
  float pb2 = wave_reduce_sum(bl0*bl0 + bl1*bl1);
  if (lane == 0) redS[wid] = pb2;
  #pragma unroll
  for (int r = 0; r < 16; ++r) {
    float pm = wave_reduce_sum(acc0[r]*acc0[r] + acc1[r]*acc1[r]);
    float pb = wave_reduce_sum(acc0[r]*bl0 + acc1[r]*bl1);
    if (lane == 0) { redM[wid][r] = pm; redB[wid][r] = pb; }
  }
  __syncthreads();
  float b2 = redS[0] + redS[1] + redS[2] + redS[3];
  #pragma unroll
  for (int r = 0; r < 16; ++r) {
    float m2 = redM[0][r]+redM[1][r]+redM[2][r]+redM[3][r];
    float mb = redB[0][r]+redB[1][r]+redB[2][r]+redB[3][r];
    float xn = xn_arr[row0 + r], art = art_arr[row0 + r];
    float mn = fmaxf(sqrtf(m2), 1e-15f);
    float t = tanhf(mn / xn * art);
    float alpha, rn;
    if (m2 > 0.f) { alpha = t / mn; rn = t; } else { alpha = 0.f; rn = 0.f; }
    if (rn > MAXN) { alpha *= MAXN / rn; rn = MAXN; }
    float x2r = rn * rn;
    float xy = alpha * mb;
    float A  = 1.f + 2.f*xy + b2;
    float Bc = 1.f - x2r;
    float den = fmaxf(1.f + 2.f*xy + x2r*b2, 1e-15f);
    float n2 = (A*A*x2r + 2.f*A*Bc*xy + Bc*Bc*b2) / (den*den);
    float nn = fmaxf(sqrtf(n2), 1e-15f);
    float sc = (nn > MAXN) ? (MAXN / nn) : 1.f;
    float G  = sc * A * alpha / den;
    float Hb = sc * Bc / den;
    size_t o = (size_t)(row0 + r) * E_;
    out[o + tid]       = G*acc0[r] + Hb*bl0;
    out[o + tid + 256] = G*acc1[r] + Hb*bl1;
  }
}

// ---- Attention v3: MFMA flash with 3-term split-bf16 (fp32-grade accuracy).
// Block = 4 waves x 64 q-rows (wave owns 16). Loop over 32 K-tiles of 64 rows.
// Fragment-ordered LDS: every MFMA operand read is one conflict-free
// ds_read_b128 at lane*16B. Fixed softmax max m=0 (scores in [-79,0]).
__global__ __launch_bounds__(256, 2) void attn_kernel(const float* __restrict__ Q,
    const float* __restrict__ K, const float* __restrict__ V,
    const float* __restrict__ qn_arr, const float* __restrict__ kn_arr,
    float* __restrict__ Out) {
  // K-frags: [dt(2)][n(4)][lane(64)][j(8)]  element = K[kr][d], kr=16n+(lane&15),
  //          d=32dt+8*(lane>>4)+j
  // V-frags: [kt(2)][dn(4)][lane(64)][j(8)] element = V[k][d], d=16dn+(lane&15),
  //          k=32kt+8*(lane>>4)+j
  // P-frags: per wave [kt(2)][lane(64)][j(8)]
  __shared__ __align__(16) unsigned short KfHi[4096], KfLo[4096];
  __shared__ __align__(16) unsigned short VfHi[4096], VfLo[4096];
  __shared__ __align__(16) unsigned short PfHi[4096], PfLo[4096];

  int tid = threadIdx.x;
  int w = tid >> 6, lane = tid & 63;
  int lane15 = lane & 15, g = lane >> 4, b3 = (lane >> 3) & 1;

  // XCD swizzle: xcd owns bh in {4*xcd .. 4*xcd+3}, all 32 qblks of a bh co-resident
  int bid = blockIdx.x;
  int xcd = bid & 7, idx = bid >> 3;
  int bh = xcd * 4 + (idx >> 5);
  int qblk = idx & 31;
  int b = bh >> 3, h = bh & 7;
  int qb = qblk * 64;
  int hoff = h * Dh_;

  // ---- preload Q fragments (A-operand; row = lane&15, k = 32*dt+8*g+j)
  int qrow_f = b * S_ + qb + w * 16 + lane15;
  short8 qhi[2], qlo[2];
  #pragma unroll
  for (int dt = 0; dt < 2; ++dt) {
    const float* qp = Q + (size_t)qrow_f * E_ + hoff + 32*dt + 8*g;
    float4 qa = *(const float4*)qp, qb4 = *(const float4*)(qp + 4);
    float qv[8] = {qa.x,qa.y,qa.z,qa.w,qb4.x,qb4.y,qb4.z,qb4.w};
    #pragma unroll
    for (int j = 0; j < 8; ++j) {
      unsigned hb = f2bf(qv[j]);
      qhi[dt][j] = (short)hb;
      qlo[dt][j] = (short)f2bf(qv[j] - bf2f(hb));
    }
  }
  // per-C-row q-norm scalars (rows rr = 4*g + i)
  float qnv[4], qd[4];
  #pragma unroll
  for (int i = 0; i < 4; ++i) {
    qnv[i] = qn_arr[(size_t)bh*S_ + qb + w*16 + 4*g + i];
    qd[i] = 1.f - qnv[i];
  }

  f32x4 Oacc[4];
  #pragma unroll
  for (int dn = 0; dn < 4; ++dn) Oacc[dn] = (f32x4){0.f,0.f,0.f,0.f};
  float lp[4] = {0.f,0.f,0.f,0.f};

  const float* Kg = K + ((size_t)b * S_) * E_ + hoff;
  const float* Vg = V + ((size_t)b * S_) * E_ + hoff;
  const float* knb = kn_arr + (size_t)bh * S_;
  int pbase = w * 1024;

  // staging index precompute
  int st_d0 = 4 * (tid & 15);          // K: d-chunk
  int st_r  = tid >> 4;                // K: row base
  int sv_d  = tid & 63;                // V: d
  int sv_k0 = 4 * (tid >> 6);          // V: k base

  #pragma unroll 1
  for (int tile = 0; tile < 32; ++tile) {
    int kb = tile * 64;
    __syncthreads();                   // prev tile's MFMA reads done
    // ---- stage K tile (rows kr, cols d): thread loads float4, writes b64 frags
    {
      int n = 0; // computed per m below
      #pragma unroll
      for (int m = 0; m < 4; ++m) {
        int kr = st_r + 16*m;
        float4 kvv = *(const float4*)(Kg + (size_t)(kb + kr) * E_ + st_d0);
        float kv[4] = {kvv.x, kvv.y, kvv.z, kvv.w};
        n = kr >> 4;
        int lane_t = (kr & 15) | (((st_d0 >> 3) & 3) << 4);
        int dt = st_d0 >> 5;
        int j0 = st_d0 & 7;
        unsigned hb0 = f2bf(kv[0]), hb1 = f2bf(kv[1]), hb2 = f2bf(kv[2]), hb3 = f2bf(kv[3]);
        unsigned lb0 = f2bf(kv[0]-bf2f(hb0)), lb1 = f2bf(kv[1]-bf2f(hb1));
        unsigned lb2 = f2bf(kv[2]-bf2f(hb2)), lb3 = f2bf(kv[3]-bf2f(hb3));
        int idxk = ((dt*4 + n)*64 + lane_t)*8 + j0;
        *(uint2*)&KfHi[idxk] = make_uint2(hb0 | (hb1<<16), hb2 | (hb3<<16));
        *(uint2*)&KfLo[idxk] = make_uint2(lb0 | (lb1<<16), lb2 | (lb3<<16));
      }
    }
    // ---- stage V tile transposed into B-frag order
    {
      #pragma unroll
      for (int m = 0; m < 4; ++m) {
        int k0 = 16*m + sv_k0;
        float vv[4];
        #pragma unroll
        for (int i = 0; i < 4; ++i)
          vv[i] = Vg[(size_t)(kb + k0 + i) * E_ + sv_d];
        int kt = k0 >> 5;
        int lane_t = (sv_d & 15) | (((k0 >> 3) & 3) << 4);
        int dn = sv_d >> 4;
        int j0 = k0 & 7;
        unsigned hb0 = f2bf(vv[0]), hb1 = f2bf(vv[1]), hb2 = f2bf(vv[2]), hb3 = f2bf(vv[3]);
        unsigned lb0 = f2bf(vv[0]-bf2f(hb0)), lb1 = f2bf(vv[1]-bf2f(hb1));
        unsigned lb2 = f2bf(vv[2]-bf2f(hb2)), lb3 = f2bf(vv[3]-bf2f(hb3));
        int idxv = ((kt*4 + dn)*64 + lane_t)*8 + j0;
        *(uint2*)&VfHi[idxv] = make_uint2(hb0 | (hb1<<16), hb2 | (hb3<<16));
        *(uint2*)&VfLo[idxv] = make_uint2(lb0 | (lb1<<16), lb2 | (lb3<<16));
      }
    }
    __syncthreads();                   // staged tiles visible

    // ---- QK^T + softmax + P fragment build
    #pragma unroll
    for (int n = 0; n < 4; ++n) {
      f32x4 Cn = (f32x4){0.f,0.f,0.f,0.f};
      #pragma unroll
      for (int dt = 0; dt < 2; ++dt) {
        short8 bh_ = *(const short8*)&KfHi[((dt*4 + n)*64 + lane)*8];
        short8 bl_ = *(const short8*)&KfLo[((dt*4 + n)*64 + lane)*8];
        Cn = __builtin_amdgcn_mfma_f32_16x16x32_bf16(qhi[dt], bh_, Cn, 0, 0, 0);
        Cn = __builtin_amdgcn_mfma_f32_16x16x32_bf16(qhi[dt], bl_, Cn, 0, 0, 0);
        Cn = __builtin_amdgcn_mfma_f32_16x16x32_bf16(qlo[dt], bh_, Cn, 0, 0, 0);
      }
      float knc = knb[kb + 16*n + lane15];
      float kd = 1.f - knc;
      int offn = (n >> 1) * 512 + (2*(n & 1) + b3) * 128 + g * 32 + (lane & 7);
      #pragma unroll
      for (int i = 0; i < 4; ++i) {
        float den = qd[i] * kd + 1e-5f;
        float delta = 2.f * (Cn[i] - qnv[i] * knc) * __frcp_rn(den);
        float sc = -0.125f * sqrtf(fmaxf(delta, 1e-5f));
        float p = __expf(sc);
        lp[i] += p;
        unsigned hb = f2bf(p);
        unsigned lb = f2bf(p - bf2f(hb));
        PfHi[pbase + offn + i*8] = (unsigned short)hb;
        PfLo[pbase + offn + i*8] = (unsigned short)lb;
      }
    }
    __syncthreads();                   // P frags visible (cross-lane within wave)

    // ---- PV
    short8 pah0 = *(const short8*)&PfHi[pbase + lane*8];
    short8 pah1 = *(const short8*)&PfHi[pbase + 512 + lane*8];
    short8 pal0 = *(const short8*)&PfLo[pbase + lane*8];
    short8 pal1 = *(const short8*)&PfLo[pbase + 512 + lane*8];
    #pragma unroll
    for (int dn = 0; dn < 4; ++dn) {
      short8 vh0 = *(const short8*)&VfHi[((0*4 + dn)*64 + lane)*8];
      short8 vl0 = *(const short8*)&VfLo[((0*4 + dn)*64 + lane)*8];
      short8 vh1 = *(const short8*)&VfHi[((1*4 + dn)*64 + lane)*8];
      short8 vl1 = *(const short8*)&VfLo[((1*4 + dn)*64 + lane)*8];
      f32x4 o = Oacc[dn];
      o = __builtin_amdgcn_mfma_f32_16x16x32_bf16(pah0, vh0, o, 0, 0, 0);
      o = __builtin_amdgcn_mfma_f32_16x16x32_bf16(pah0, vl0, o, 0, 0, 0);
      o = __builtin_amdgcn_mfma_f32_16x16x32_bf16(pal0, vh0, o, 0, 0, 0);
      o = __builtin_amdgcn_mfma_f32_16x16x32_bf16(pah1, vh1, o, 0, 0, 0);
      o = __builtin_amdgcn_mfma_f32_16x16x32_bf16(pah1, vl1, o, 0, 0, 0);
      o = __builtin_amdgcn_mfma_f32_16x16x32_bf16(pal1, vh1, o, 0, 0, 0);
      Oacc[dn] = o;
    }
  }

  // ---- epilogue: reduce l over the 16-lane col groups, normalize, write
  #pragma unroll
  for (int i = 0; i < 4; ++i) {
    lp[i] += __shfl_xor(lp[i], 1, 64);
    lp[i] += __shfl_xor(lp[i], 2, 64);
    lp[i] += __shfl_xor(lp[i], 4, 64);
    lp[i] += __shfl_xor(lp[i], 8, 64);
    lp[i] = 1.f / lp[i];
  }
  #pragma unroll
  for (int i = 0; i < 4; ++i) {
    size_t orow = (size_t)(b * S_ + qb + w*16 + 4*g + i) * E_ + hoff;
    #pragma unroll
    for (int dn = 0; dn < 4; ++dn)
      Out[orow + 16*dn + lane15] = Oacc[dn][i] * lp[i];
  }
}

extern "C" void kernel_launch(void* const* d_in, const int* in_sizes, int n_in,
                              void* d_out, int out_size, void* d_ws, size_t ws_size,
                              hipStream_t stream) {
  const float* x  = (const float*)d_in[0];
  const float* Wq = (const float*)d_in[1];
  const float* bq = (const float*)d_in[2];
  const float* Wk = (const float*)d_in[3];
  const float* bk = (const float*)d_in[4];
  const float* Wv = (const float*)d_in[5];
  const float* bv = (const float*)d_in[6];
  const float* Wo = (const float*)d_in[7];
  const float* bo = (const float*)d_in[8];
  float* out = (float*)d_out;

  float* ws   = (float*)d_ws;
  float* q    = ws;                         // BS_*E_
  float* k    = q  + (size_t)BS_*E_;        // BS_*E_
  float* v    = k  + (size_t)BS_*E_;        // BS_*E_
  float* xn   = v  + (size_t)BS_*E_;        // BS_
  float* art  = xn  + BS_;                  // BS_
  float* xn2  = art + BS_;                  // BS_
  float* art2 = xn2 + BS_;                  // BS_
  float* qn   = art2 + BS_;                 // B_*H_*S_
  float* kn   = qn + (size_t)B_*H_*S_;      // B_*H_*S_

  row_stats_kernel<<<dim3(BS_/4), dim3(256), 0, stream>>>(x, xn, art);
  hyp_linear_kernel<<<dim3(BS_/16), dim3(256), 0, stream>>>(x, Wq, bq, xn, art, q);
  hyp_linear_kernel<<<dim3(BS_/16), dim3(256), 0, stream>>>(x, Wk, bk, xn, art, k);
  hyp_linear_kernel<<<dim3(BS_/16), dim3(256), 0, stream>>>(x, Wv, bv, xn, art, v);
  head_norm_kernel<<<dim3(BS_/4, 2), dim3(256), 0, stream>>>(q, k, qn, kn);
  attn_kernel<<<dim3(1024), dim3(256), 0, stream>>>(q, k, v, qn, kn, out);
  row_stats_kernel<<<dim3(BS_/4), dim3(256), 0, stream>>>(out, xn2, art2);
  hyp_linear_kernel<<<dim3(BS_/16), dim3(256), 0, stream>>>(out, Wo, bo, xn2, art2, out);
}

// Round 4
// 1001.718 us; speedup vs baseline: 3.3984x; 1.2578x over previous
//
#include <hip/hip_runtime.h>
#include <math.h>

#define B_ 4
#define S_ 2048
#define E_ 512
#define H_ 8
#define Dh_ 64
#define BS_ (B_*S_)
#define MAXN 0.996f   // (1 - 4e-3)/sqrt(c), c=1

typedef __attribute__((ext_vector_type(8))) short short8;
typedef __attribute__((ext_vector_type(4))) float f32x4;

__device__ __forceinline__ float wave_reduce_sum(float v) {
  #pragma unroll
  for (int off = 32; off > 0; off >>= 1) v += __shfl_xor(v, off, 64);
  return v;
}

__device__ __forceinline__ unsigned f2bf(float x) {            // RNE f32->bf16 bits
  unsigned u = __float_as_uint(x);
  return (u + 0x7fffu + ((u >> 16) & 1u)) >> 16;
}
__device__ __forceinline__ float bf2f(unsigned b) {
  return __uint_as_float(b << 16);
}

// ---- P1: per-row stats: xn = max(||row||,1e-15), art = artanh(clip(xn))
__global__ __launch_bounds__(256) void row_stats_kernel(const float* __restrict__ X,
                                                        float* __restrict__ xn_out,
                                                        float* __restrict__ art_out) {
  int row = blockIdx.x * 4 + (threadIdx.x >> 6);
  int lane = threadIdx.x & 63;
  const float4* xr = (const float4*)(X + (size_t)row * E_) + lane * 2;
  float4 a = xr[0], b = xr[1];
  float s = a.x*a.x + a.y*a.y + a.z*a.z + a.w*a.w
          + b.x*b.x + b.y*b.y + b.z*b.z + b.w*b.w;
  s = wave_reduce_sum(s);
  if (lane == 0) {
    float xn = fmaxf(sqrtf(s), 1e-15f);
    float aa = fminf(xn, 1.f - 1e-7f);
    xn_out[row] = xn;
    art_out[row] = 0.5f * (log1pf(aa) - log1pf(-aa));
  }
}

// ---- P2: per-(b,h,s) head norms of Q and K, clipped to 1-1e-5
__global__ __launch_bounds__(256) void head_norm_kernel(const float* __restrict__ Q,
                                                        const float* __restrict__ K,
                                                        float* __restrict__ qn,
                                                        float* __restrict__ kn) {
  int row = blockIdx.x * 4 + (threadIdx.x >> 6);
  int lane = threadIdx.x & 63;
  const float* src = blockIdx.y ? K : Q;
  float* dst = blockIdx.y ? kn : qn;
  const float4* xr = (const float4*)(src + (size_t)row * E_) + lane * 2;
  float4 a = xr[0], b = xr[1];
  float s = a.x*a.x + a.y*a.y + a.z*a.z + a.w*a.w
          + b.x*b.x + b.y*b.y + b.z*b.z + b.w*b.w;
  s += __shfl_xor(s, 1, 64); s += __shfl_xor(s, 2, 64); s += __shfl_xor(s, 4, 64);
  if ((lane & 7) == 0) {
    int h = lane >> 3;
    int b_ = row >> 11, sidx = row & (S_ - 1);
    dst[((size_t)(b_*H_ + h))*S_ + sidx] = fminf(s, 1.f - 1e-5f);
  }
}

// ---- pack one of 4 W matrices into B-frag-ordered bf16 hi/lo
// layout (shorts): Wp[mat][ ((n*16 + t)*2 + hl)*512 + lane*8 + j ]
// element: W[16n + (lane&15)][32t + 8*(lane>>4) + j]
__global__ __launch_bounds__(64) void pack_w_kernel(const float* __restrict__ W0,
    const float* __restrict__ W1, const float* __restrict__ W2,
    const float* __restrict__ W3, unsigned short* __restrict__ Wp) {
  const float* W = (blockIdx.y == 0) ? W0 : (blockIdx.y == 1) ? W1
                 : (blockIdx.y == 2) ? W2 : W3;
  unsigned short* dst = Wp + (size_t)blockIdx.y * 524288;
  int l = threadIdx.x;
  int n = blockIdx.x;
  int col = 16*n + (l & 15);
  int k0 = 8 * (l >> 4);
  #pragma unroll 1
  for (int t = 0; t < 16; ++t) {
    const float* wp_ = W + (size_t)col * E_ + 32*t + k0;
    float4 a0 = *(const float4*)wp_, a1 = *(const float4*)(wp_ + 4);
    float av[8] = {a0.x,a0.y,a0.z,a0.w,a1.x,a1.y,a1.z,a1.w};
    short8 hi, lo;
    #pragma unroll
    for (int j = 0; j < 8; ++j) {
      unsigned hb = f2bf(av[j]);
      hi[j] = (short)hb;
      lo[j] = (short)f2bf(av[j] - bf2f(hb));
    }
    unsigned short* o = dst + ((size_t)(n*16 + t)*2)*512 + l*8;
    *(short8*)o = hi;
    *(short8*)(o + 512) = lo;
  }
}

// ---- hyp_linear v2: MFMA GEMM (3-term split bf16) + Mobius epilogue.
// One wave per 16 rows x all 512 cols (full-row ownership -> intra-wave epilogue).
// A converted in-register from fp32; B-frags read straight from L2 (W is 1MB,
// resident; no LDS, no barriers).
__global__ __launch_bounds__(64, 2) void hyp_linear_mfma(const float* __restrict__ X,
    const unsigned short* __restrict__ Wp, const float* __restrict__ bvec,
    const float* __restrict__ xn_arr, const float* __restrict__ art_arr,
    float* __restrict__ out) {
  int l = threadIdx.x;
  int R = blockIdx.x;                      // row-tile: rows 16R..16R+15
  int row_in = l & 15, g = l >> 4;
  const float* xrow = X + (size_t)(R*16 + row_in)*E_ + 8*g;
  f32x4 acc[32];
  #pragma unroll
  for (int n = 0; n < 32; ++n) acc[n] = (f32x4){0.f,0.f,0.f,0.f};

  #pragma unroll 1
  for (int t = 0; t < 16; ++t) {
    float4 a0 = *(const float4*)(xrow + 32*t);
    float4 a1 = *(const float4*)(xrow + 32*t + 4);
    float av[8] = {a0.x,a0.y,a0.z,a0.w,a1.x,a1.y,a1.z,a1.w};
    short8 ahi, alo;
    #pragma unroll
    for (int j = 0; j < 8; ++j) {
      unsigned hb = f2bf(av[j]);
      ahi[j] = (short)hb;
      alo[j] = (short)f2bf(av[j] - bf2f(hb));
    }
    const unsigned short* wb = Wp + (size_t)t * 1024 + l * 8;
    #pragma unroll
    for (int n = 0; n < 32; ++n) {
      short8 bhi = *(const short8*)(wb + n*16384);
      short8 blo = *(const short8*)(wb + n*16384 + 512);
      acc[n] = __builtin_amdgcn_mfma_f32_16x16x32_bf16(ahi, bhi, acc[n], 0, 0, 0);
      acc[n] = __builtin_amdgcn_mfma_f32_16x16x32_bf16(ahi, blo, acc[n], 0, 0, 0);
      acc[n] = __builtin_amdgcn_mfma_f32_16x16x32_bf16(alo, bhi, acc[n], 0, 0, 0);
    }
  }

  // ---- epilogue: C/D mapping row = 4g+i, col = 16n+row_in
  float bl[32];
  #pragma unroll
  for (int n = 0; n < 32; ++n) bl[n] = bvec[16*n + row_in];
  float b2 = 0.f, m2p[4] = {0.f,0.f,0.f,0.f}, mbp[4] = {0.f,0.f,0.f,0.f};
  #pragma unroll
  for (int n = 0; n < 32; ++n) {
    b2 += bl[n]*bl[n];
    #pragma unroll
    for (int i = 0; i < 4; ++i) {
      m2p[i] = fmaf(acc[n][i], acc[n][i], m2p[i]);
      mbp[i] = fmaf(acc[n][i], bl[n], mbp[i]);
    }
  }
  #pragma unroll
  for (int off = 1; off <= 8; off <<= 1) {
    b2 += __shfl_xor(b2, off, 64);
    #pragma unroll
    for (int i = 0; i < 4; ++i) {
      m2p[i] += __shfl_xor(m2p[i], off, 64);
      mbp[i] += __shfl_xor(mbp[i], off, 64);
    }
  }
  float G[4], Hb[4];
  #pragma unroll
  for (int i = 0; i < 4; ++i) {
    int row = R*16 + 4*g + i;
    float xn = xn_arr[row], art = art_arr[row];
    float m2 = m2p[i], mb = mbp[i];
    float mn = fmaxf(sqrtf(m2), 1e-15f);
    float t = tanhf(mn / xn * art);
    float alpha, rn;
    if (m2 > 0.f) { alpha = t / mn; rn = t; } else { alpha = 0.f; rn = 0.f; }
    if (rn > MAXN) { alpha *= MAXN / rn; rn = MAXN; }          // project(res)
    float x2r = rn * rn;
    float xy = alpha * mb;
    float A  = 1.f + 2.f*xy + b2;
    float Bc = 1.f - x2r;
    float den = fmaxf(1.f + 2.f*xy + x2r*b2, 1e-15f);
    float n2 = (A*A*x2r + 2.f*A*Bc*xy + Bc*Bc*b2) / (den*den);
    float nn = fmaxf(sqrtf(n2), 1e-15f);
    float sc = (nn > MAXN) ? (MAXN / nn) : 1.f;                // project(add)
    G[i]  = sc * A * alpha / den;
    Hb[i] = sc * Bc / den;
  }
  #pragma unroll
  for (int n = 0; n < 32; ++n) {
    #pragma unroll
    for (int i = 0; i < 4; ++i) {
      out[(size_t)(R*16 + 4*g + i)*E_ + 16*n + row_in] =
          G[i]*acc[n][i] + Hb[i]*bl[n];
    }
  }
}

// ---- Attention (unchanged from round 3): MFMA flash, split-bf16, fixed m=0.
__global__ __launch_bounds__(256, 2) void attn_kernel(const float* __restrict__ Q,
    const float* __restrict__ K, const float* __restrict__ V,
    const float* __restrict__ qn_arr, const float* __restrict__ kn_arr,
    float* __restrict__ Out) {
  __shared__ __align__(16) unsigned short KfHi[4096], KfLo[4096];
  __shared__ __align__(16) unsigned short VfHi[4096], VfLo[4096];
  __shared__ __align__(16) unsigned short PfHi[4096], PfLo[4096];

  int tid = threadIdx.x;
  int w = tid >> 6, lane = tid & 63;
  int lane15 = lane & 15, g = lane >> 4, b3 = (lane >> 3) & 1;

  int bid = blockIdx.x;
  int xcd = bid & 7, idx = bid >> 3;
  int bh = xcd * 4 + (idx >> 5);
  int qblk = idx & 31;
  int b = bh >> 3, h = bh & 7;
  int qb = qblk * 64;
  int hoff = h * Dh_;

  int qrow_f = b * S_ + qb + w * 16 + lane15;
  short8 qhi[2], qlo[2];
  #pragma unroll
  for (int dt = 0; dt < 2; ++dt) {
    const float* qp = Q + (size_t)qrow_f * E_ + hoff + 32*dt + 8*g;
    float4 qa = *(const float4*)qp, qb4 = *(const float4*)(qp + 4);
    float qv[8] = {qa.x,qa.y,qa.z,qa.w,qb4.x,qb4.y,qb4.z,qb4.w};
    #pragma unroll
    for (int j = 0; j < 8; ++j) {
      unsigned hb = f2bf(qv[j]);
      qhi[dt][j] = (short)hb;
      qlo[dt][j] = (short)f2bf(qv[j] - bf2f(hb));
    }
  }
  float qnv[4], qd[4];
  #pragma unroll
  for (int i = 0; i < 4; ++i) {
    qnv[i] = qn_arr[(size_t)bh*S_ + qb + w*16 + 4*g + i];
    qd[i] = 1.f - qnv[i];
  }

  f32x4 Oacc[4];
  #pragma unroll
  for (int dn = 0; dn < 4; ++dn) Oacc[dn] = (f32x4){0.f,0.f,0.f,0.f};
  float lp[4] = {0.f,0.f,0.f,0.f};

  const float* Kg = K + ((size_t)b * S_) * E_ + hoff;
  const float* Vg = V + ((size_t)b * S_) * E_ + hoff;
  const float* knb = kn_arr + (size_t)bh * S_;
  int pbase = w * 1024;

  int st_d0 = 4 * (tid & 15);
  int st_r  = tid >> 4;
  int sv_d  = tid & 63;
  int sv_k0 = 4 * (tid >> 6);

  #pragma unroll 1
  for (int tile = 0; tile < 32; ++tile) {
    int kb = tile * 64;
    __syncthreads();
    {
      #pragma unroll
      for (int m = 0; m < 4; ++m) {
        int kr = st_r + 16*m;
        float4 kvv = *(const float4*)(Kg + (size_t)(kb + kr) * E_ + st_d0);
        float kv[4] = {kvv.x, kvv.y, kvv.z, kvv.w};
        int n = kr >> 4;
        int lane_t = (kr & 15) | (((st_d0 >> 3) & 3) << 4);
        int dt = st_d0 >> 5;
        int j0 = st_d0 & 7;
        unsigned hb0 = f2bf(kv[0]), hb1 = f2bf(kv[1]), hb2 = f2bf(kv[2]), hb3 = f2bf(kv[3]);
        unsigned lb0 = f2bf(kv[0]-bf2f(hb0)), lb1 = f2bf(kv[1]-bf2f(hb1));
        unsigned lb2 = f2bf(kv[2]-bf2f(hb2)), lb3 = f2bf(kv[3]-bf2f(hb3));
        int idxk = ((dt*4 + n)*64 + lane_t)*8 + j0;
        *(uint2*)&KfHi[idxk] = make_uint2(hb0 | (hb1<<16), hb2 | (hb3<<16));
        *(uint2*)&KfLo[idxk] = make_uint2(lb0 | (lb1<<16), lb2 | (lb3<<16));
      }
    }
    {
      #pragma unroll
      for (int m = 0; m < 4; ++m) {
        int k0 = 16*m + sv_k0;
        float vv[4];
        #pragma unroll
        for (int i = 0; i < 4; ++i)
          vv[i] = Vg[(size_t)(kb + k0 + i) * E_ + sv_d];
        int kt = k0 >> 5;
        int lane_t = (sv_d & 15) | (((k0 >> 3) & 3) << 4);
        int dn = sv_d >> 4;
        int j0 = k0 & 7;
        unsigned hb0 = f2bf(vv[0]), hb1 = f2bf(vv[1]), hb2 = f2bf(vv[2]), hb3 = f2bf(vv[3]);
        unsigned lb0 = f2bf(vv[0]-bf2f(hb0)), lb1 = f2bf(vv[1]-bf2f(hb1));
        unsigned lb2 = f2bf(vv[2]-bf2f(hb2)), lb3 = f2bf(vv[3]-bf2f(hb3));
        int idxv = ((kt*4 + dn)*64 + lane_t)*8 + j0;
        *(uint2*)&VfHi[idxv] = make_uint2(hb0 | (hb1<<16), hb2 | (hb3<<16));
        *(uint2*)&VfLo[idxv] = make_uint2(lb0 | (lb1<<16), lb2 | (lb3<<16));
      }
    }
    __syncthreads();

    #pragma unroll
    for (int n = 0; n < 4; ++n) {
      f32x4 Cn = (f32x4){0.f,0.f,0.f,0.f};
      #pragma unroll
      for (int dt = 0; dt < 2; ++dt) {
        short8 bh_ = *(const short8*)&KfHi[((dt*4 + n)*64 + lane)*8];
        short8 bl_ = *(const short8*)&KfLo[((dt*4 + n)*64 + lane)*8];
        Cn = __builtin_amdgcn_mfma_f32_16x16x32_bf16(qhi[dt], bh_, Cn, 0, 0, 0);
        Cn = __builtin_amdgcn_mfma_f32_16x16x32_bf16(qhi[dt], bl_, Cn, 0, 0, 0);
        Cn = __builtin_amdgcn_mfma_f32_16x16x32_bf16(qlo[dt], bh_, Cn, 0, 0, 0);
      }
      float knc = knb[kb + 16*n + lane15];
      float kd = 1.f - knc;
      int offn = (n >> 1) * 512 + (2*(n & 1) + b3) * 128 + g * 32 + (lane & 7);
      #pragma unroll
      for (int i = 0; i < 4; ++i) {
        float den = qd[i] * kd + 1e-5f;
        float delta = 2.f * (Cn[i] - qnv[i] * knc) * __frcp_rn(den);
        float sc = -0.125f * sqrtf(fmaxf(delta, 1e-5f));
        float p = __expf(sc);
        lp[i] += p;
        unsigned hb = f2bf(p);
        unsigned lb = f2bf(p - bf2f(hb));
        PfHi[pbase + offn + i*8] = (unsigned short)hb;
        PfLo[pbase + offn + i*8] = (unsigned short)lb;
      }
    }
    __syncthreads();

    short8 pah0 = *(const short8*)&PfHi[pbase + lane*8];
    short8 pah1 = *(const short8*)&PfHi[pbase + 512 + lane*8];
    short8 pal0 = *(const short8*)&PfLo[pbase + lane*8];
    short8 pal1 = *(const short8*)&PfLo[pbase + 512 + lane*8];
    #pragma unroll
    for (int dn = 0; dn < 4; ++dn) {
      short8 vh0 = *(const short8*)&VfHi[((0*4 + dn)*64 + lane)*8];
      short8 vl0 = *(const short8*)&VfLo[((0*4 + dn)*64 + lane)*8];
      short8 vh1 = *(const short8*)&VfHi[((1*4 + dn)*64 + lane)*8];
      short8 vl1 = *(const short8*)&VfLo[((1*4 + dn)*64 + lane)*8];
      f32x4 o = Oacc[dn];
      o = __builtin_amdgcn_mfma_f32_16x16x32_bf16(pah0, vh0, o, 0, 0, 0);
      o = __builtin_amdgcn_mfma_f32_16x16x32_bf16(pah0, vl0, o, 0, 0, 0);
      o = __builtin_amdgcn_mfma_f32_16x16x32_bf16(pal0, vh0, o, 0, 0, 0);
      o = __builtin_amdgcn_mfma_f32_16x16x32_bf16(pah1, vh1, o, 0, 0, 0);
      o = __builtin_amdgcn_mfma_f32_16x16x32_bf16(pah1, vl1, o, 0, 0, 0);
      o = __builtin_amdgcn_mfma_f32_16x16x32_bf16(pal1, vh1, o, 0, 0, 0);
      Oacc[dn] = o;
    }
  }

  #pragma unroll
  for (int i = 0; i < 4; ++i) {
    lp[i] += __shfl_xor(lp[i], 1, 64);
    lp[i] += __shfl_xor(lp[i], 2, 64);
    lp[i] += __shfl_xor(lp[i], 4, 64);
    lp[i] += __shfl_xor(lp[i], 8, 64);
    lp[i] = 1.f / lp[i];
  }
  #pragma unroll
  for (int i = 0; i < 4; ++i) {
    size_t orow = (size_t)(b * S_ + qb + w*16 + 4*g + i) * E_ + hoff;
    #pragma unroll
    for (int dn = 0; dn < 4; ++dn)
      Out[orow + 16*dn + lane15] = Oacc[dn][i] * lp[i];
  }
}

extern "C" void kernel_launch(void* const* d_in, const int* in_sizes, int n_in,
                              void* d_out, int out_size, void* d_ws, size_t ws_size,
                              hipStream_t stream) {
  const float* x  = (const float*)d_in[0];
  const float* Wq = (const float*)d_in[1];
  const float* bq = (const float*)d_in[2];
  const float* Wk = (const float*)d_in[3];
  const float* bk = (const float*)d_in[4];
  const float* Wv = (const float*)d_in[5];
  const float* bv = (const float*)d_in[6];
  const float* Wo = (const float*)d_in[7];
  const float* bo = (const float*)d_in[8];
  float* out = (float*)d_out;

  float* ws   = (float*)d_ws;
  float* q    = ws;                         // BS_*E_
  float* k    = q  + (size_t)BS_*E_;        // BS_*E_
  float* v    = k  + (size_t)BS_*E_;        // BS_*E_
  float* xn   = v  + (size_t)BS_*E_;        // BS_
  float* art  = xn  + BS_;                  // BS_
  float* xn2  = art + BS_;                  // BS_
  float* art2 = xn2 + BS_;                  // BS_
  float* qn   = art2 + BS_;                 // B_*H_*S_
  float* kn   = qn + (size_t)B_*H_*S_;      // B_*H_*S_
  unsigned short* Wp = (unsigned short*)(kn + (size_t)B_*H_*S_);  // 4*524288 shorts = 4 MB
  // total ~52.6 MiB of ws

  pack_w_kernel<<<dim3(32, 4), dim3(64), 0, stream>>>(Wq, Wk, Wv, Wo, Wp);
  row_stats_kernel<<<dim3(BS_/4), dim3(256), 0, stream>>>(x, xn, art);
  hyp_linear_mfma<<<dim3(BS_/16), dim3(64), 0, stream>>>(x, Wp,            bq, xn, art, q);
  hyp_linear_mfma<<<dim3(BS_/16), dim3(64), 0, stream>>>(x, Wp + 524288,   bk, xn, art, k);
  hyp_linear_mfma<<<dim3(BS_/16), dim3(64), 0, stream>>>(x, Wp + 2*524288, bv, xn, art, v);
  head_norm_kernel<<<dim3(BS_/4, 2), dim3(256), 0, stream>>>(q, k, qn, kn);
  attn_kernel<<<dim3(1024), dim3(256), 0, stream>>>(q, k, v, qn, kn, out);
  row_stats_kernel<<<dim3(BS_/4), dim3(256), 0, stream>>>(out, xn2, art2);
  hyp_linear_mfma<<<dim3(BS_/16), dim3(64), 0, stream>>>(out, Wp + 3*524288, bo, xn2, art2, out);
}

// Round 5
// 491.527 us; speedup vs baseline: 6.9258x; 2.0380x over previous
//
#include <hip/hip_runtime.h>
#include <math.h>

#define B_ 4
#define S_ 2048
#define E_ 512
#define H_ 8
#define Dh_ 64
#define BS_ (B_*S_)
#define MAXN 0.996f   // (1 - 4e-3)/sqrt(c), c=1

typedef __attribute__((ext_vector_type(8))) short short8;
typedef __attribute__((ext_vector_type(4))) float f32x4;

__device__ __forceinline__ float wave_reduce_sum(float v) {
  #pragma unroll
  for (int off = 32; off > 0; off >>= 1) v += __shfl_xor(v, off, 64);
  return v;
}

__device__ __forceinline__ unsigned f2bf(float x) {            // RNE f32->bf16 bits
  unsigned u = __float_as_uint(x);
  return (u + 0x7fffu + ((u >> 16) & 1u)) >> 16;
}
__device__ __forceinline__ float bf2f(unsigned b) {
  return __uint_as_float(b << 16);
}

// ---- per-row stats: xn = max(||row||,1e-15), art = artanh(clip(xn))
__global__ __launch_bounds__(256) void row_stats_kernel(const float* __restrict__ X,
                                                        float* __restrict__ xn_out,
                                                        float* __restrict__ art_out) {
  int row = blockIdx.x * 4 + (threadIdx.x >> 6);
  int lane = threadIdx.x & 63;
  const float4* xr = (const float4*)(X + (size_t)row * E_) + lane * 2;
  float4 a = xr[0], b = xr[1];
  float s = a.x*a.x + a.y*a.y + a.z*a.z + a.w*a.w
          + b.x*b.x + b.y*b.y + b.z*b.z + b.w*b.w;
  s = wave_reduce_sum(s);
  if (lane == 0) {
    float xn = fmaxf(sqrtf(s), 1e-15f);
    float aa = fminf(xn, 1.f - 1e-7f);
    xn_out[row] = xn;
    art_out[row] = 0.5f * (log1pf(aa) - log1pf(-aa));
  }
}

// ---- pack W matrices into B-frag-ordered bf16 hi/lo (unchanged layout)
// Wp[mat][ ((n*16 + t)*2 + hl)*512 + lane*8 + j ]
// element: W[16n + (lane&15)][32t + 8*(lane>>4) + j]
__global__ __launch_bounds__(64) void pack_w_kernel(const float* __restrict__ W0,
    const float* __restrict__ W1, const float* __restrict__ W2,
    const float* __restrict__ W3, unsigned short* __restrict__ Wp) {
  const float* W = (blockIdx.y == 0) ? W0 : (blockIdx.y == 1) ? W1
                 : (blockIdx.y == 2) ? W2 : W3;
  unsigned short* dst = Wp + (size_t)blockIdx.y * 524288;
  int l = threadIdx.x;
  int n = blockIdx.x;
  int col = 16*n + (l & 15);
  int k0 = 8 * (l >> 4);
  #pragma unroll 1
  for (int t = 0; t < 16; ++t) {
    const float* wp_ = W + (size_t)col * E_ + 32*t + k0;
    float4 a0 = *(const float4*)wp_, a1 = *(const float4*)(wp_ + 4);
    float av[8] = {a0.x,a0.y,a0.z,a0.w,a1.x,a1.y,a1.z,a1.w};
    short8 hi, lo;
    #pragma unroll
    for (int j = 0; j < 8; ++j) {
      unsigned hb = f2bf(av[j]);
      hi[j] = (short)hb;
      lo[j] = (short)f2bf(av[j] - bf2f(hb));
    }
    unsigned short* o = dst + ((size_t)(n*16 + t)*2)*512 + l*8;
    *(short8*)o = hi;
    *(short8*)(o + 512) = lo;
  }
}

// ---- hyp_linear v3: 4-wave in-block split-K MFMA GEMM + Mobius epilogue.
// Block = 16 rows x 512 cols; wave w handles K-range [128w, 128w+128).
// LDS combine, then per-MODE output:
//  MODE 0 (Q): frag-ordered bf16 hi+lo + per-head norms
//  MODE 1 (K): frag-ordered bf16 hi (A/K layout) + per-head norms
//  MODE 2 (V): frag-ordered bf16 hi (transposed V layout)
//  MODE 3 (O): fp32 rows
template<int MODE>
__global__ __launch_bounds__(256, 2) void hyp_linear_pack(const float* __restrict__ X,
    const unsigned short* __restrict__ Wp, const float* __restrict__ bvec,
    const float* __restrict__ xn_arr, const float* __restrict__ art_arr,
    float* __restrict__ outF, unsigned short* __restrict__ outHi,
    unsigned short* __restrict__ outLo, float* __restrict__ normOut) {
  int tid = threadIdx.x;
  int w = tid >> 6, l = tid & 63;
  int l15 = l & 15, g = l >> 4;
  int R = blockIdx.x;                       // rows 16R..16R+15
  f32x4 acc[32];
  #pragma unroll
  for (int n = 0; n < 32; ++n) acc[n] = (f32x4){0.f,0.f,0.f,0.f};

  const float* xrow = X + (size_t)(R*16 + l15)*E_ + 8*g;
  #pragma unroll 1
  for (int tt = 0; tt < 4; ++tt) {
    int t = 4*w + tt;
    float4 a0 = *(const float4*)(xrow + 32*t);
    float4 a1 = *(const float4*)(xrow + 32*t + 4);
    float av[8] = {a0.x,a0.y,a0.z,a0.w,a1.x,a1.y,a1.z,a1.w};
    short8 ahi, alo;
    #pragma unroll
    for (int j = 0; j < 8; ++j) {
      unsigned hb = f2bf(av[j]);
      ahi[j] = (short)hb;
      alo[j] = (short)f2bf(av[j] - bf2f(hb));
    }
    const unsigned short* wb = Wp + (size_t)t * 1024 + (size_t)l * 8;
    #pragma unroll
    for (int n = 0; n < 32; ++n) {
      short8 bhi = *(const short8*)(wb + (size_t)n*16384);
      short8 blo = *(const short8*)(wb + (size_t)n*16384 + 512);
      acc[n] = __builtin_amdgcn_mfma_f32_16x16x32_bf16(ahi, bhi, acc[n], 0, 0, 0);
      acc[n] = __builtin_amdgcn_mfma_f32_16x16x32_bf16(ahi, blo, acc[n], 0, 0, 0);
      acc[n] = __builtin_amdgcn_mfma_f32_16x16x32_bf16(alo, bhi, acc[n], 0, 0, 0);
    }
  }

  // ---- cross-wave K-combine: wave w ends owning n in [8w, 8w+8)
  __shared__ float cb[4][64][33];
  float facc[8][4];
  #pragma unroll 1
  for (int r = 0; r < 4; ++r) {
    if (r) __syncthreads();
    #pragma unroll
    for (int s = 0; s < 8; ++s)
      #pragma unroll
      for (int i = 0; i < 4; ++i)
        cb[w][l][s*4+i] = acc[8*r+s][i];
    __syncthreads();
    if (w == r) {
      #pragma unroll
      for (int s = 0; s < 8; ++s)
        #pragma unroll
        for (int i = 0; i < 4; ++i)
          facc[s][i] = cb[0][l][4*s+i] + cb[1][l][4*s+i]
                     + cb[2][l][4*s+i] + cb[3][l][4*s+i];
    }
  }

  // ---- epilogue scalars
  float bl[8];
  #pragma unroll
  for (int s = 0; s < 8; ++s) bl[s] = bvec[16*(8*w+s) + l15];
  float m2p[4] = {0.f,0.f,0.f,0.f}, mbp[4] = {0.f,0.f,0.f,0.f}, b2p = 0.f;
  #pragma unroll
  for (int s = 0; s < 8; ++s) {
    b2p += bl[s]*bl[s];
    #pragma unroll
    for (int i = 0; i < 4; ++i) {
      m2p[i] = fmaf(facc[s][i], facc[s][i], m2p[i]);
      mbp[i] = fmaf(facc[s][i], bl[s], mbp[i]);
    }
  }
  #pragma unroll
  for (int off = 1; off <= 8; off <<= 1) {
    b2p += __shfl_xor(b2p, off, 64);
    #pragma unroll
    for (int i = 0; i < 4; ++i) {
      m2p[i] += __shfl_xor(m2p[i], off, 64);
      mbp[i] += __shfl_xor(mbp[i], off, 64);
    }
  }
  __shared__ float smM[4][4][4], smB[4][4][4], smb2[4];
  __syncthreads();                 // cb no longer needed; reuse-safe ordering
  if (l == 0) smb2[w] = b2p;
  if (l15 == 0) {
    #pragma unroll
    for (int i = 0; i < 4; ++i) { smM[w][g][i] = m2p[i]; smB[w][g][i] = mbp[i]; }
  }
  __syncthreads();
  float b2 = smb2[0] + smb2[1] + smb2[2] + smb2[3];
  float G[4], Hc[4];
  #pragma unroll
  for (int i = 0; i < 4; ++i) {
    float m2 = smM[0][g][i]+smM[1][g][i]+smM[2][g][i]+smM[3][g][i];
    float mb = smB[0][g][i]+smB[1][g][i]+smB[2][g][i]+smB[3][g][i];
    int row = R*16 + 4*g + i;
    float xn = xn_arr[row], art = art_arr[row];
    float mn = fmaxf(sqrtf(m2), 1e-15f);
    float t = tanhf(mn / xn * art);
    float alpha, rn;
    if (m2 > 0.f) { alpha = t / mn; rn = t; } else { alpha = 0.f; rn = 0.f; }
    if (rn > MAXN) { alpha *= MAXN / rn; rn = MAXN; }          // project(res)
    float x2r = rn * rn;
    float xy = alpha * mb;
    float A  = 1.f + 2.f*xy + b2;
    float Bc = 1.f - x2r;
    float den = fmaxf(1.f + 2.f*xy + x2r*b2, 1e-15f);
    float n2 = (A*A*x2r + 2.f*A*Bc*xy + Bc*Bc*b2) / (den*den);
    float nn = fmaxf(sqrtf(n2), 1e-15f);
    float sc = (nn > MAXN) ? (MAXN / nn) : 1.f;                // project(add)
    G[i]  = sc * A * alpha / den;
    Hc[i] = sc * Bc / den;
  }

  // ---- outputs
  #pragma unroll
  for (int i = 0; i < 4; ++i) {
    int grow = R*16 + 4*g + i;
    if (MODE == 3) {
      #pragma unroll
      for (int s = 0; s < 8; ++s)
        outF[(size_t)grow*E_ + 16*(8*w+s) + l15] = G[i]*facc[s][i] + Hc[i]*bl[s];
    } else {
      int bb = grow >> 11, seq = grow & 2047;
      int tile = seq >> 6;
      float hn0 = 0.f, hn1 = 0.f;
      #pragma unroll
      for (int s = 0; s < 8; ++s) {
        int col = 16*(8*w+s) + l15;
        float v = G[i]*facc[s][i] + Hc[i]*bl[s];
        int h = col >> 6, c = col & 63;
        size_t base;
        if (MODE == 2) {   // V layout: chunk (kt*4+dn)*64 + ((c&15)|(gp<<4)), j = seq&7
          int kt = (seq >> 5) & 1, gp = (seq >> 3) & 3, jv = seq & 7;
          int dn = c >> 4, lt = (c & 15) | (gp << 4);
          base = ((size_t)((bb*8 + h)*32 + tile))*4096 + (size_t)((kt*4+dn)*64 + lt)*8 + jv;
        } else {           // Q/K layout: chunk (dt*4+nf)*64 + (lt15|(m<<4)), j = c&7
          int nf = (seq >> 4) & 3, lt15 = seq & 15;
          int dt = c >> 5, m = (c >> 3) & 3, j = c & 7;
          base = ((size_t)((bb*8 + h)*32 + tile))*4096 + (size_t)((dt*4+nf)*64 + (lt15|(m<<4)))*8 + j;
        }
        unsigned hb = f2bf(v);
        outHi[base] = (unsigned short)hb;
        if (MODE == 0) outLo[base] = (unsigned short)f2bf(v - bf2f(hb));
        if (MODE <= 1) { if (s < 4) hn0 += v*v; else hn1 += v*v; }
      }
      if (MODE <= 1) {
        hn0 += __shfl_xor(hn0,1,64); hn0 += __shfl_xor(hn0,2,64);
        hn0 += __shfl_xor(hn0,4,64); hn0 += __shfl_xor(hn0,8,64);
        hn1 += __shfl_xor(hn1,1,64); hn1 += __shfl_xor(hn1,2,64);
        hn1 += __shfl_xor(hn1,4,64); hn1 += __shfl_xor(hn1,8,64);
        if (l15 == 0) {
          normOut[((size_t)(bb*8 + 2*w + 0))*S_ + seq] = fminf(hn0, 1.f - 1e-5f);
          normOut[((size_t)(bb*8 + 2*w + 1))*S_ + seq] = fminf(hn1, 1.f - 1e-5f);
        }
      }
    }
  }
}

// ---- Attention v4: all operands pre-packed bf16 frags; staging = pure copies.
// QK = qhi*khi + qlo*khi; P,V hi-only. Fixed softmax max m=0.
// Double-buffered K/V (1 barrier/tile); P LDS XOR-swizzled (conflict-free).
__global__ __launch_bounds__(256, 3) void attn_kernel(
    const unsigned short* __restrict__ Qhi, const unsigned short* __restrict__ Qlo,
    const unsigned short* __restrict__ Khi, const unsigned short* __restrict__ Vhi,
    const float* __restrict__ qn_arr, const float* __restrict__ kn_arr,
    float* __restrict__ Out) {
  __shared__ __align__(16) unsigned short Kf[2][4096], Vf[2][4096];
  __shared__ __align__(16) unsigned short Pf[4][1024];
  __shared__ float knsh[2][64];

  int tid = threadIdx.x;
  int w = tid >> 6, l = tid & 63;
  int l15 = l & 15, g = l >> 4;

  int bid = blockIdx.x;                 // XCD swizzle: xcd owns bh 4*xcd..4*xcd+3
  int xcd = bid & 7, idx = bid >> 3;
  int bh = xcd * 4 + (idx >> 5);
  int qblk = idx & 31;
  int b = bh >> 3, h = bh & 7;
  int qb = qblk * 64;

  // Q fragments (pre-packed, hi+lo)
  const unsigned short* qbase = Qhi + ((size_t)(bh*32 + qblk))*4096;
  const unsigned short* qbasel = Qlo + ((size_t)(bh*32 + qblk))*4096;
  short8 qhi[2], qlo[2];
  #pragma unroll
  for (int dt = 0; dt < 2; ++dt) {
    qhi[dt] = *(const short8*)(qbase  + (size_t)((dt*4 + w)*64 + l)*8);
    qlo[dt] = *(const short8*)(qbasel + (size_t)((dt*4 + w)*64 + l)*8);
  }
  float qnv[4], qd[4];
  #pragma unroll
  for (int i = 0; i < 4; ++i) {
    qnv[i] = qn_arr[(size_t)bh*S_ + qb + 16*w + 4*g + i];
    qd[i] = 1.f - qnv[i];
  }

  f32x4 Oacc[4];
  #pragma unroll
  for (int dn = 0; dn < 4; ++dn) Oacc[dn] = (f32x4){0.f,0.f,0.f,0.f};
  float lp[4] = {0.f,0.f,0.f,0.f};

  const unsigned short* Kbh = Khi + ((size_t)bh*32)*4096;
  const unsigned short* Vbh = Vhi + ((size_t)bh*32)*4096;
  const float* knp = kn_arr + (size_t)bh*S_;

  // prologue: stage tile 0
  {
    float4 k0 = *(const float4*)(Kbh + (size_t)tid*8);
    float4 k1 = *(const float4*)(Kbh + (size_t)(tid+256)*8);
    float4 v0 = *(const float4*)(Vbh + (size_t)tid*8);
    float4 v1 = *(const float4*)(Vbh + (size_t)(tid+256)*8);
    *(float4*)&Kf[0][tid*8] = k0; *(float4*)&Kf[0][(tid+256)*8] = k1;
    *(float4*)&Vf[0][tid*8] = v0; *(float4*)&Vf[0][(tid+256)*8] = v1;
    if (tid < 64) knsh[0][tid] = knp[tid];
  }
  __syncthreads();

  #pragma unroll 1
  for (int tile = 0; tile < 32; ++tile) {
    int cur = tile & 1;
    if (tile < 31) {                    // stage tile+1 into buf^1
      const unsigned short* kp = Kbh + ((size_t)(tile+1))*4096;
      const unsigned short* vp = Vbh + ((size_t)(tile+1))*4096;
      float4 k0 = *(const float4*)(kp + (size_t)tid*8);
      float4 k1 = *(const float4*)(kp + (size_t)(tid+256)*8);
      float4 v0 = *(const float4*)(vp + (size_t)tid*8);
      float4 v1 = *(const float4*)(vp + (size_t)(tid+256)*8);
      *(float4*)&Kf[cur^1][tid*8] = k0; *(float4*)&Kf[cur^1][(tid+256)*8] = k1;
      *(float4*)&Vf[cur^1][tid*8] = v0; *(float4*)&Vf[cur^1][(tid+256)*8] = v1;
      if (tid < 64) knsh[cur^1][tid] = knp[(tile+1)*64 + tid];
    }
    // ---- QK^T + softmax + P store (wave-local, swizzled)
    #pragma unroll
    for (int n = 0; n < 4; ++n) {
      f32x4 Cn = (f32x4){0.f,0.f,0.f,0.f};
      #pragma unroll
      for (int dt = 0; dt < 2; ++dt) {
        short8 kfr = *(const short8*)&Kf[cur][((dt*4 + n)*64 + l)*8];
        Cn = __builtin_amdgcn_mfma_f32_16x16x32_bf16(qhi[dt], kfr, Cn, 0, 0, 0);
        Cn = __builtin_amdgcn_mfma_f32_16x16x32_bf16(qlo[dt], kfr, Cn, 0, 0, 0);
      }
      float knc = knsh[cur][16*n + l15];
      float kd = 1.f - knc;
      #pragma unroll
      for (int i = 0; i < 4; ++i) {
        float den = qd[i]*kd + 1e-5f;
        float delta = 2.f*(Cn[i] - qnv[i]*knc) * __frcp_rn(den);
        float sc = -0.125f * sqrtf(fmaxf(delta, 1e-5f));
        float p = __expf(sc);
        unsigned hb = f2bf(p);
        lp[i] += bf2f(hb);
        int c = (n >> 1)*64 + (4*g + i) + 16*((2*n + (l15 >> 3)) & 3);
        int cs = c ^ ((c >> 3) & 7);
        Pf[w][cs*8 + (l15 & 7)] = (unsigned short)hb;
      }
    }
    // ---- PV (wave-local P read through swizzle; within-wave lgkm ordering)
    short8 pa0, pa1;
    { int c = l;       int cs = c ^ ((c >> 3) & 7); pa0 = *(const short8*)&Pf[w][cs*8]; }
    { int c = 64 + l;  int cs = c ^ ((c >> 3) & 7); pa1 = *(const short8*)&Pf[w][cs*8]; }
    #pragma unroll
    for (int dn = 0; dn < 4; ++dn) {
      short8 v0 = *(const short8*)&Vf[cur][((0*4 + dn)*64 + l)*8];
      short8 v1 = *(const short8*)&Vf[cur][((1*4 + dn)*64 + l)*8];
      f32x4 o = Oacc[dn];
      o = __builtin_amdgcn_mfma_f32_16x16x32_bf16(pa0, v0, o, 0, 0, 0);
      o = __builtin_amdgcn_mfma_f32_16x16x32_bf16(pa1, v1, o, 0, 0, 0);
      Oacc[dn] = o;
    }
    __syncthreads();
  }

  // ---- epilogue
  #pragma unroll
  for (int i = 0; i < 4; ++i) {
    lp[i] += __shfl_xor(lp[i], 1, 64);
    lp[i] += __shfl_xor(lp[i], 2, 64);
    lp[i] += __shfl_xor(lp[i], 4, 64);
    lp[i] += __shfl_xor(lp[i], 8, 64);
    lp[i] = 1.f / lp[i];
  }
  #pragma unroll
  for (int i = 0; i < 4; ++i) {
    size_t orow = (size_t)(b*S_ + qb + 16*w + 4*g + i)*E_ + h*Dh_;
    #pragma unroll
    for (int dn = 0; dn < 4; ++dn)
      Out[orow + 16*dn + l15] = Oacc[dn][i] * lp[i];
  }
}

extern "C" void kernel_launch(void* const* d_in, const int* in_sizes, int n_in,
                              void* d_out, int out_size, void* d_ws, size_t ws_size,
                              hipStream_t stream) {
  const float* x  = (const float*)d_in[0];
  const float* Wq = (const float*)d_in[1];
  const float* bq = (const float*)d_in[2];
  const float* Wk = (const float*)d_in[3];
  const float* bk = (const float*)d_in[4];
  const float* Wv = (const float*)d_in[5];
  const float* bv = (const float*)d_in[6];
  const float* Wo = (const float*)d_in[7];
  const float* bo = (const float*)d_in[8];
  float* out = (float*)d_out;

  char* p = (char*)d_ws;
  unsigned short* Wp  = (unsigned short*)p; p += (size_t)4  << 20;  // 4 MB
  unsigned short* Qhi = (unsigned short*)p; p += (size_t)8  << 20;
  unsigned short* Qlo = (unsigned short*)p; p += (size_t)8  << 20;
  unsigned short* Khi = (unsigned short*)p; p += (size_t)8  << 20;
  unsigned short* Vhi = (unsigned short*)p; p += (size_t)8  << 20;
  float* ao   = (float*)p; p += (size_t)16 << 20;                   // attn out fp32
  float* xn   = (float*)p; p += BS_ * 4;
  float* art  = (float*)p; p += BS_ * 4;
  float* xn2  = (float*)p; p += BS_ * 4;
  float* art2 = (float*)p; p += BS_ * 4;
  float* qn   = (float*)p; p += (size_t)B_*H_*S_ * 4;
  float* kn   = (float*)p; p += (size_t)B_*H_*S_ * 4;
  // total ~= 52.6 MB

  pack_w_kernel<<<dim3(32, 4), dim3(64), 0, stream>>>(Wq, Wk, Wv, Wo, Wp);
  row_stats_kernel<<<dim3(BS_/4), dim3(256), 0, stream>>>(x, xn, art);
  hyp_linear_pack<0><<<dim3(BS_/16), dim3(256), 0, stream>>>(x, Wp,            bq, xn, art, nullptr, Qhi, Qlo, qn);
  hyp_linear_pack<1><<<dim3(BS_/16), dim3(256), 0, stream>>>(x, Wp + 524288,   bk, xn, art, nullptr, Khi, nullptr, kn);
  hyp_linear_pack<2><<<dim3(BS_/16), dim3(256), 0, stream>>>(x, Wp + 2*524288, bv, xn, art, nullptr, Vhi, nullptr, nullptr);
  attn_kernel<<<dim3(1024), dim3(256), 0, stream>>>(Qhi, Qlo, Khi, Vhi, qn, kn, ao);
  row_stats_kernel<<<dim3(BS_/4), dim3(256), 0, stream>>>(ao, xn2, art2);
  hyp_linear_pack<3><<<dim3(BS_/16), dim3(256), 0, stream>>>(ao, Wp + 3*524288, bo, xn2, art2, out, nullptr, nullptr, nullptr);
}

// Round 6
// 265.379 us; speedup vs baseline: 12.8278x; 1.8522x over previous
//
#include <hip/hip_runtime.h>
#include <math.h>

#define B_ 4
#define S_ 2048
#define E_ 512
#define H_ 8
#define Dh_ 64
#define BS_ (B_*S_)
#define MAXN 0.996f   // (1 - 4e-3)/sqrt(c), c=1

typedef __attribute__((ext_vector_type(8))) short short8;
typedef __attribute__((ext_vector_type(4))) float f32x4;

__device__ __forceinline__ float wave_reduce_sum(float v) {
  #pragma unroll
  for (int off = 32; off > 0; off >>= 1) v += __shfl_xor(v, off, 64);
  return v;
}

__device__ __forceinline__ unsigned f2bf(float x) {            // RNE f32->bf16 bits
  unsigned u = __float_as_uint(x);
  return (u + 0x7fffu + ((u >> 16) & 1u)) >> 16;
}
__device__ __forceinline__ float bf2f(unsigned b) {
  return __uint_as_float(b << 16);
}

__device__ __forceinline__ void gload_lds16(const void* g, void* lds) {
  __builtin_amdgcn_global_load_lds(
      (const __attribute__((address_space(1))) unsigned int*)g,
      (__attribute__((address_space(3))) unsigned int*)lds, 16, 0, 0);
}

// ---- per-row stats: xn = max(||row||,1e-15), art = artanh(clip(xn))
__global__ __launch_bounds__(256) void row_stats_kernel(const float* __restrict__ X,
                                                        float* __restrict__ xn_out,
                                                        float* __restrict__ art_out) {
  int row = blockIdx.x * 4 + (threadIdx.x >> 6);
  int lane = threadIdx.x & 63;
  const float4* xr = (const float4*)(X + (size_t)row * E_) + lane * 2;
  float4 a = xr[0], b = xr[1];
  float s = a.x*a.x + a.y*a.y + a.z*a.z + a.w*a.w
          + b.x*b.x + b.y*b.y + b.z*b.z + b.w*b.w;
  s = wave_reduce_sum(s);
  if (lane == 0) {
    float xn = fmaxf(sqrtf(s), 1e-15f);
    float aa = fminf(xn, 1.f - 1e-7f);
    xn_out[row] = xn;
    art_out[row] = 0.5f * (log1pf(aa) - log1pf(-aa));
  }
}

// ---- pack W matrices: t-major B-frag order (contiguous 64KB per K-step)
// Wp[mat][ ((t*32 + n)*2 + hl)*512 + l*8 + j ]
// element: W[16n + (l&15)][32t + 8*(l>>4) + j]
__global__ __launch_bounds__(64) void pack_w_kernel(const float* __restrict__ W0,
    const float* __restrict__ W1, const float* __restrict__ W2,
    const float* __restrict__ W3, unsigned short* __restrict__ Wp) {
  const float* W = (blockIdx.y == 0) ? W0 : (blockIdx.y == 1) ? W1
                 : (blockIdx.y == 2) ? W2 : W3;
  unsigned short* dst = Wp + (size_t)blockIdx.y * 524288;
  int l = threadIdx.x;
  int n = blockIdx.x;
  int col = 16*n + (l & 15);
  int k0 = 8 * (l >> 4);
  #pragma unroll 1
  for (int t = 0; t < 16; ++t) {
    const float* wp_ = W + (size_t)col * E_ + 32*t + k0;
    float4 a0 = *(const float4*)wp_, a1 = *(const float4*)(wp_ + 4);
    float av[8] = {a0.x,a0.y,a0.z,a0.w,a1.x,a1.y,a1.z,a1.w};
    short8 hi, lo;
    #pragma unroll
    for (int j = 0; j < 8; ++j) {
      unsigned hb = f2bf(av[j]);
      hi[j] = (short)hb;
      lo[j] = (short)f2bf(av[j] - bf2f(hb));
    }
    unsigned short* o = dst + ((size_t)(t*32 + n)*2)*512 + l*8;
    *(short8*)o = hi;
    *(short8*)(o + 512) = lo;
  }
}

// ---- hyp_linear v4: 8-wave, M=32, double-buffered global_load_lds W staging.
// Wave (rh = w&1, nh = w>>1): rows rh*16+[0,16), n-tiles [8nh, 8nh+8).
// MODE 1: frag-ordered bf16 hi (QK layout) + per-head norms
// MODE 2: frag-ordered bf16 hi (V layout)
// MODE 3: fp32 rows
template<int MODE>
__global__ __launch_bounds__(512, 1) void hyp_linear_pack(const float* __restrict__ X,
    const unsigned short* __restrict__ Wp, const float* __restrict__ bvec,
    const float* __restrict__ xn_arr, const float* __restrict__ art_arr,
    float* __restrict__ outF, unsigned short* __restrict__ outHi,
    float* __restrict__ normOut) {
  __shared__ __align__(16) unsigned short Wt[2][32768];   // 2 x 64KB
  __shared__ float smM[4][2][4][4], smB[4][2][4][4], smb2[8];
  int tid = threadIdx.x;
  int w = tid >> 6, l = tid & 63;
  int l15 = l & 15, g = l >> 4;
  int rh = w & 1, nh = w >> 1;
  int R = blockIdx.x;                       // rows 32R .. 32R+31

  f32x4 acc[8];
  #pragma unroll
  for (int nn = 0; nn < 8; ++nn) acc[nn] = (f32x4){0.f,0.f,0.f,0.f};
  const float* xrow = X + (size_t)(R*32 + rh*16 + l15)*E_ + 8*g;

  // prologue: stage t=0 (each wave stages its own 8KB span; consumers = same wave pair)
  {
    const unsigned short* src = Wp + (size_t)w*4096 + (size_t)l*8;
    #pragma unroll
    for (int c = 0; c < 8; ++c)
      gload_lds16(src + c*512, &Wt[0][w*4096 + l*8 + c*512]);
  }
  asm volatile("s_waitcnt vmcnt(0)" ::: "memory");
  __syncthreads();

  #pragma unroll 1
  for (int t = 0; t < 16; ++t) {
    int cur = t & 1;
    if (t < 15) {
      const unsigned short* src = Wp + (size_t)(t+1)*32768 + (size_t)w*4096 + (size_t)l*8;
      #pragma unroll
      for (int c = 0; c < 8; ++c)
        gload_lds16(src + c*512, &Wt[cur^1][w*4096 + l*8 + c*512]);
    }
    float4 a0 = *(const float4*)(xrow + 32*t);
    float4 a1 = *(const float4*)(xrow + 32*t + 4);
    float av[8] = {a0.x,a0.y,a0.z,a0.w,a1.x,a1.y,a1.z,a1.w};
    short8 ahi, alo;
    #pragma unroll
    for (int j = 0; j < 8; ++j) {
      unsigned hb = f2bf(av[j]);
      ahi[j] = (short)hb;
      alo[j] = (short)f2bf(av[j] - bf2f(hb));
    }
    const unsigned short* wb = &Wt[cur][(nh*16)*512] + l*8;
    #pragma unroll
    for (int nn = 0; nn < 8; ++nn) {
      short8 bhi = *(const short8*)(wb + nn*1024);
      short8 blo = *(const short8*)(wb + nn*1024 + 512);
      acc[nn] = __builtin_amdgcn_mfma_f32_16x16x32_bf16(ahi, bhi, acc[nn], 0, 0, 0);
      acc[nn] = __builtin_amdgcn_mfma_f32_16x16x32_bf16(ahi, blo, acc[nn], 0, 0, 0);
      acc[nn] = __builtin_amdgcn_mfma_f32_16x16x32_bf16(alo, bhi, acc[nn], 0, 0, 0);
    }
    asm volatile("s_waitcnt vmcnt(0)" ::: "memory");
    __syncthreads();
  }

  // ---- epilogue scalars (rows rh*16 + 4g + i; cols 16(8nh+s)+l15)
  float bl[8];
  #pragma unroll
  for (int s = 0; s < 8; ++s) bl[s] = bvec[16*(8*nh+s) + l15];
  float m2p[4] = {0.f,0.f,0.f,0.f}, mbp[4] = {0.f,0.f,0.f,0.f}, b2p = 0.f;
  #pragma unroll
  for (int s = 0; s < 8; ++s) {
    b2p += bl[s]*bl[s];
    #pragma unroll
    for (int i = 0; i < 4; ++i) {
      m2p[i] = fmaf(acc[s][i], acc[s][i], m2p[i]);
      mbp[i] = fmaf(acc[s][i], bl[s], mbp[i]);
    }
  }
  #pragma unroll
  for (int off = 1; off <= 8; off <<= 1) {
    b2p += __shfl_xor(b2p, off, 64);
    #pragma unroll
    for (int i = 0; i < 4; ++i) {
      m2p[i] += __shfl_xor(m2p[i], off, 64);
      mbp[i] += __shfl_xor(mbp[i], off, 64);
    }
  }
  if (l == 0) smb2[w] = b2p;
  if (l15 == 0) {
    #pragma unroll
    for (int i = 0; i < 4; ++i) { smM[nh][rh][g][i] = m2p[i]; smB[nh][rh][g][i] = mbp[i]; }
  }
  __syncthreads();
  float b2 = smb2[rh] + smb2[2+rh] + smb2[4+rh] + smb2[6+rh];
  float G[4], Hc[4];
  #pragma unroll
  for (int i = 0; i < 4; ++i) {
    float m2 = smM[0][rh][g][i]+smM[1][rh][g][i]+smM[2][rh][g][i]+smM[3][rh][g][i];
    float mb = smB[0][rh][g][i]+smB[1][rh][g][i]+smB[2][rh][g][i]+smB[3][rh][g][i];
    int row = R*32 + rh*16 + 4*g + i;
    float xn = xn_arr[row], art = art_arr[row];
    float mn = fmaxf(sqrtf(m2), 1e-15f);
    float t = tanhf(mn / xn * art);
    float alpha, rn;
    if (m2 > 0.f) { alpha = t / mn; rn = t; } else { alpha = 0.f; rn = 0.f; }
    if (rn > MAXN) { alpha *= MAXN / rn; rn = MAXN; }          // project(res)
    float x2r = rn * rn;
    float xy = alpha * mb;
    float A  = 1.f + 2.f*xy + b2;
    float Bc = 1.f - x2r;
    float den = fmaxf(1.f + 2.f*xy + x2r*b2, 1e-15f);
    float n2 = (A*A*x2r + 2.f*A*Bc*xy + Bc*Bc*b2) / (den*den);
    float nn = fmaxf(sqrtf(n2), 1e-15f);
    float sc = (nn > MAXN) ? (MAXN / nn) : 1.f;                // project(add)
    G[i]  = sc * A * alpha / den;
    Hc[i] = sc * Bc / den;
  }

  // ---- outputs
  #pragma unroll
  for (int i = 0; i < 4; ++i) {
    int grow = R*32 + rh*16 + 4*g + i;
    if (MODE == 3) {
      #pragma unroll
      for (int s = 0; s < 8; ++s)
        outF[(size_t)grow*E_ + 16*(8*nh+s) + l15] = G[i]*acc[s][i] + Hc[i]*bl[s];
    } else {
      int bb = grow >> 11, seq = grow & 2047;
      int tile = seq >> 6;
      float hn0 = 0.f, hn1 = 0.f;
      #pragma unroll
      for (int s = 0; s < 8; ++s) {
        int col = 16*(8*nh+s) + l15;
        float v = G[i]*acc[s][i] + Hc[i]*bl[s];
        int h = col >> 6, c = col & 63;
        size_t base;
        if (MODE == 2) {   // V layout
          int kt = (seq >> 5) & 1, gp = (seq >> 3) & 3, jv = seq & 7;
          int dn = c >> 4, lt = (c & 15) | (gp << 4);
          base = ((size_t)((bb*8 + h)*32 + tile))*4096 + (size_t)((kt*4+dn)*64 + lt)*8 + jv;
        } else {           // Q/K layout
          int nf = (seq >> 4) & 3, lt15 = seq & 15;
          int dt = c >> 5, m = (c >> 3) & 3, j = c & 7;
          base = ((size_t)((bb*8 + h)*32 + tile))*4096 + (size_t)((dt*4+nf)*64 + (lt15|(m<<4)))*8 + j;
        }
        outHi[base] = (unsigned short)f2bf(v);
        if (MODE == 1) { if (s < 4) hn0 += v*v; else hn1 += v*v; }
      }
      if (MODE == 1) {
        hn0 += __shfl_xor(hn0,1,64); hn0 += __shfl_xor(hn0,2,64);
        hn0 += __shfl_xor(hn0,4,64); hn0 += __shfl_xor(hn0,8,64);
        hn1 += __shfl_xor(hn1,1,64); hn1 += __shfl_xor(hn1,2,64);
        hn1 += __shfl_xor(hn1,4,64); hn1 += __shfl_xor(hn1,8,64);
        if (l15 == 0) {
          normOut[((size_t)(bb*8 + 2*nh + 0))*S_ + seq] = fminf(hn0, 1.f - 1e-5f);
          normOut[((size_t)(bb*8 + 2*nh + 1))*S_ + seq] = fminf(hn1, 1.f - 1e-5f);
        }
      }
    }
  }
}

// ---- Attention v5: Q hi-only (1 MFMA per frag pair), HW-approx rcp/rsq/exp2.
__global__ __launch_bounds__(256, 3) void attn_kernel(
    const unsigned short* __restrict__ Qhi, const unsigned short* __restrict__ Khi,
    const unsigned short* __restrict__ Vhi,
    const float* __restrict__ qn_arr, const float* __restrict__ kn_arr,
    float* __restrict__ Out) {
  __shared__ __align__(16) unsigned short Kf[2][4096], Vf[2][4096];
  __shared__ __align__(16) unsigned short Pf[4][1024];
  __shared__ float knsh[2][64];

  int tid = threadIdx.x;
  int w = tid >> 6, l = tid & 63;
  int l15 = l & 15, g = l >> 4;

  int bid = blockIdx.x;                 // XCD swizzle: xcd owns bh 4*xcd..4*xcd+3
  int xcd = bid & 7, idx = bid >> 3;
  int bh = xcd * 4 + (idx >> 5);
  int qblk = idx & 31;
  int b = bh >> 3, h = bh & 7;
  int qb = qblk * 64;

  const unsigned short* qbase = Qhi + ((size_t)(bh*32 + qblk))*4096;
  short8 qhi[2];
  #pragma unroll
  for (int dt = 0; dt < 2; ++dt)
    qhi[dt] = *(const short8*)(qbase + (size_t)((dt*4 + w)*64 + l)*8);
  float qnv[4], qd[4];
  #pragma unroll
  for (int i = 0; i < 4; ++i) {
    qnv[i] = qn_arr[(size_t)bh*S_ + qb + 16*w + 4*g + i];
    qd[i] = 1.f - qnv[i];
  }

  f32x4 Oacc[4];
  #pragma unroll
  for (int dn = 0; dn < 4; ++dn) Oacc[dn] = (f32x4){0.f,0.f,0.f,0.f};
  float lp[4] = {0.f,0.f,0.f,0.f};

  const unsigned short* Kbh = Khi + ((size_t)bh*32)*4096;
  const unsigned short* Vbh = Vhi + ((size_t)bh*32)*4096;
  const float* knp = kn_arr + (size_t)bh*S_;

  {
    float4 k0 = *(const float4*)(Kbh + (size_t)tid*8);
    float4 k1 = *(const float4*)(Kbh + (size_t)(tid+256)*8);
    float4 v0 = *(const float4*)(Vbh + (size_t)tid*8);
    float4 v1 = *(const float4*)(Vbh + (size_t)(tid+256)*8);
    *(float4*)&Kf[0][tid*8] = k0; *(float4*)&Kf[0][(tid+256)*8] = k1;
    *(float4*)&Vf[0][tid*8] = v0; *(float4*)&Vf[0][(tid+256)*8] = v1;
    if (tid < 64) knsh[0][tid] = knp[tid];
  }
  __syncthreads();

  #pragma unroll 1
  for (int tile = 0; tile < 32; ++tile) {
    int cur = tile & 1;
    if (tile < 31) {
      const unsigned short* kp = Kbh + ((size_t)(tile+1))*4096;
      const unsigned short* vp = Vbh + ((size_t)(tile+1))*4096;
      float4 k0 = *(const float4*)(kp + (size_t)tid*8);
      float4 k1 = *(const float4*)(kp + (size_t)(tid+256)*8);
      float4 v0 = *(const float4*)(vp + (size_t)tid*8);
      float4 v1 = *(const float4*)(vp + (size_t)(tid+256)*8);
      *(float4*)&Kf[cur^1][tid*8] = k0; *(float4*)&Kf[cur^1][(tid+256)*8] = k1;
      *(float4*)&Vf[cur^1][tid*8] = v0; *(float4*)&Vf[cur^1][(tid+256)*8] = v1;
      if (tid < 64) knsh[cur^1][tid] = knp[(tile+1)*64 + tid];
    }
    // ---- QK^T + softmax + P store
    #pragma unroll
    for (int n = 0; n < 4; ++n) {
      f32x4 Cn = (f32x4){0.f,0.f,0.f,0.f};
      #pragma unroll
      for (int dt = 0; dt < 2; ++dt) {
        short8 kfr = *(const short8*)&Kf[cur][((dt*4 + n)*64 + l)*8];
        Cn = __builtin_amdgcn_mfma_f32_16x16x32_bf16(qhi[dt], kfr, Cn, 0, 0, 0);
      }
      float knc = knsh[cur][16*n + l15];
      float kd = 1.f - knc;
      int cbase = (n >> 1)*64 + 16*((2*n + (l15 >> 3)) & 3) + 4*g;
      int csb = cbase ^ ((cbase >> 3) & 7);      // cs_i = csb ^ i (no carry: cbase%4==0)
      int j7 = l15 & 7;
      #pragma unroll
      for (int i = 0; i < 4; ++i) {
        float den = qd[i]*kd + 1e-5f;
        float r = __builtin_amdgcn_rcpf(den);
        float num = Cn[i] - qnv[i]*knc;
        float delta = fmaxf(2.f*num*r, 1e-5f);
        float sq = delta * __builtin_amdgcn_rsqf(delta);       // sqrt(delta)
        float p = __builtin_amdgcn_exp2f(-0.18033688f * sq);   // exp(-sqrt/8)
        unsigned hb = f2bf(p);
        lp[i] += bf2f(hb);
        Pf[w][((csb ^ i) << 3) + j7] = (unsigned short)hb;
      }
    }
    // ---- PV
    short8 pa0, pa1;
    { int c = l;       int cs = c ^ ((c >> 3) & 7); pa0 = *(const short8*)&Pf[w][cs*8]; }
    { int c = 64 + l;  int cs = c ^ ((c >> 3) & 7); pa1 = *(const short8*)&Pf[w][cs*8]; }
    #pragma unroll
    for (int dn = 0; dn < 4; ++dn) {
      short8 v0 = *(const short8*)&Vf[cur][((0*4 + dn)*64 + l)*8];
      short8 v1 = *(const short8*)&Vf[cur][((1*4 + dn)*64 + l)*8];
      f32x4 o = Oacc[dn];
      o = __builtin_amdgcn_mfma_f32_16x16x32_bf16(pa0, v0, o, 0, 0, 0);
      o = __builtin_amdgcn_mfma_f32_16x16x32_bf16(pa1, v1, o, 0, 0, 0);
      Oacc[dn] = o;
    }
    __syncthreads();
  }

  #pragma unroll
  for (int i = 0; i < 4; ++i) {
    lp[i] += __shfl_xor(lp[i], 1, 64);
    lp[i] += __shfl_xor(lp[i], 2, 64);
    lp[i] += __shfl_xor(lp[i], 4, 64);
    lp[i] += __shfl_xor(lp[i], 8, 64);
    lp[i] = 1.f / lp[i];
  }
  #pragma unroll
  for (int i = 0; i < 4; ++i) {
    size_t orow = (size_t)(b*S_ + qb + 16*w + 4*g + i)*E_ + h*Dh_;
    #pragma unroll
    for (int dn = 0; dn < 4; ++dn)
      Out[orow + 16*dn + l15] = Oacc[dn][i] * lp[i];
  }
}

extern "C" void kernel_launch(void* const* d_in, const int* in_sizes, int n_in,
                              void* d_out, int out_size, void* d_ws, size_t ws_size,
                              hipStream_t stream) {
  const float* x  = (const float*)d_in[0];
  const float* Wq = (const float*)d_in[1];
  const float* bq = (const float*)d_in[2];
  const float* Wk = (const float*)d_in[3];
  const float* bk = (const float*)d_in[4];
  const float* Wv = (const float*)d_in[5];
  const float* bv = (const float*)d_in[6];
  const float* Wo = (const float*)d_in[7];
  const float* bo = (const float*)d_in[8];
  float* out = (float*)d_out;

  char* p = (char*)d_ws;
  unsigned short* Wp  = (unsigned short*)p; p += (size_t)4  << 20;  // 4 MB
  unsigned short* Qhi = (unsigned short*)p; p += (size_t)8  << 20;
  unsigned short* Khi = (unsigned short*)p; p += (size_t)8  << 20;
  unsigned short* Vhi = (unsigned short*)p; p += (size_t)8  << 20;
  float* ao   = (float*)p; p += (size_t)16 << 20;                   // attn out fp32
  float* xn   = (float*)p; p += BS_ * 4;
  float* art  = (float*)p; p += BS_ * 4;
  float* xn2  = (float*)p; p += BS_ * 4;
  float* art2 = (float*)p; p += BS_ * 4;
  float* qn   = (float*)p; p += (size_t)B_*H_*S_ * 4;
  float* kn   = (float*)p; p += (size_t)B_*H_*S_ * 4;
  // total ~= 44.6 MB

  pack_w_kernel<<<dim3(32, 4), dim3(64), 0, stream>>>(Wq, Wk, Wv, Wo, Wp);
  row_stats_kernel<<<dim3(BS_/4), dim3(256), 0, stream>>>(x, xn, art);
  hyp_linear_pack<1><<<dim3(BS_/32), dim3(512), 0, stream>>>(x, Wp,            bq, xn, art, nullptr, Qhi, qn);
  hyp_linear_pack<1><<<dim3(BS_/32), dim3(512), 0, stream>>>(x, Wp + 524288,   bk, xn, art, nullptr, Khi, kn);
  hyp_linear_pack<2><<<dim3(BS_/32), dim3(512), 0, stream>>>(x, Wp + 2*524288, bv, xn, art, nullptr, Vhi, nullptr);
  attn_kernel<<<dim3(1024), dim3(256), 0, stream>>>(Qhi, Khi, Vhi, qn, kn, ao);
  row_stats_kernel<<<dim3(BS_/4), dim3(256), 0, stream>>>(ao, xn2, art2);
  hyp_linear_pack<3><<<dim3(BS_/32), dim3(512), 0, stream>>>(ao, Wp + 3*524288, bo, xn2, art2, out, nullptr, nullptr);
}